// Round 1
// baseline (1473.799 us; speedup 1.0000x reference)
//
#include <hip/hip_runtime.h>
#include <math.h>

#define N_NODES 50000
#define N_EDGES 800000
#define HID 64
#define HEADS 8
#define DH 8
#define LAYERS 6
#define EDGE_DIM 16
#define SIGN_DIM 8
#define EPS 1e-5f

// ---------------- node features: x[n][d] = sum_slot (emb_strand[xn[n][slot]][d] + emb_pos[slot][d])
__global__ __launch_bounds__(256) void k_node_feat(
    const int* __restrict__ xn, const float* __restrict__ emb_s,
    const float* __restrict__ emb_p, float* __restrict__ x) {
    int idx = blockIdx.x * 256 + threadIdx.x;  // n*64+d
    if (idx >= N_NODES * HID) return;
    int n = idx >> 6, d = idx & 63;
    float acc = 0.f;
#pragma unroll
    for (int s = 0; s < 4; ++s) {
        int id = xn[n * 4 + s];
        acc += emb_s[id * HID + d] + emb_p[s * HID + d];
    }
    x[idx] = acc;
}

// ---------------- CSR build
__global__ __launch_bounds__(256) void k_count(const int* __restrict__ dst, int* __restrict__ cnt) {
    int e = blockIdx.x * 256 + threadIdx.x;
    if (e < N_EDGES) atomicAdd(&cnt[dst[e]], 1);
}

__global__ __launch_bounds__(1024) void k_scan(const int* __restrict__ cnt, int* __restrict__ rowptr) {
    __shared__ int wsum[16];
    __shared__ int sbase;
    int t = threadIdx.x;
    int lane = t & 63, w = t >> 6;
    if (t == 0) { sbase = 0; rowptr[0] = 0; }
    __syncthreads();
    for (int start = 0; start < N_NODES; start += 1024) {
        int i = start + t;
        int val = (i < N_NODES) ? cnt[i] : 0;
        int incl = val;
#pragma unroll
        for (int o = 1; o < 64; o <<= 1) {
            int u = __shfl_up(incl, o);
            if (lane >= o) incl += u;
        }
        if (lane == 63) wsum[w] = incl;
        __syncthreads();
        int woff = 0;
        for (int j = 0; j < w; ++j) woff += wsum[j];
        int g = sbase + woff + incl;
        if (i < N_NODES) rowptr[i + 1] = g;
        __syncthreads();
        if (t == 1023) sbase = g;
        __syncthreads();
    }
}

__global__ __launch_bounds__(256) void k_fill(
    const int* __restrict__ src, const int* __restrict__ dst,
    const int* __restrict__ rowptr, int* __restrict__ cursor,
    int* __restrict__ src_sorted, int* __restrict__ eorig) {
    int e = blockIdx.x * 256 + threadIdx.x;
    if (e >= N_EDGES) return;
    int d = dst[e];
    int pos = atomicAdd(&cursor[d], 1);
    int idx = rowptr[d] + pos;
    src_sorted[idx] = src[e];
    eorig[idx] = e;
}

// ---------------- edge features in dst-sorted order: ef[i][c] = [strand|sign]@We + be
__global__ __launch_bounds__(256) void k_ef(
    const int* __restrict__ eorig, const int* __restrict__ label,
    const int* __restrict__ sign, const float* __restrict__ emb_s,
    const float* __restrict__ emb_sg, const float* __restrict__ We,
    const float* __restrict__ be, float* __restrict__ ef) {
    int gid = blockIdx.x * 256 + threadIdx.x;
    int i = gid >> 4;
    int c = gid & 15;
    if (i >= N_EDGES) return;
    int e = eorig[i];
    int lb = label[e], sg = sign[e];
    float acc = be[c];
    const float* er = emb_s + lb * HID;
#pragma unroll
    for (int j = 0; j < HID; ++j) acc += er[j] * We[j * EDGE_DIM + c];
    const float* sr = emb_sg + sg * SIGN_DIM;
#pragma unroll
    for (int j = 0; j < SIGN_DIM; ++j) acc += sr[j] * We[(HID + j) * EDGE_DIM + c];
    ef[i * EDGE_DIM + c] = acc;
}

// ---------------- fused q/k/v/skip projection: 16 nodes per 256-thread block
#define RB 16
__global__ __launch_bounds__(256) void k_qkvs(
    const float* __restrict__ x,
    const float* __restrict__ Wq, const float* __restrict__ bq,
    const float* __restrict__ Wk, const float* __restrict__ bk,
    const float* __restrict__ Wv, const float* __restrict__ bv,
    const float* __restrict__ Ws, const float* __restrict__ bs,
    float* __restrict__ q, float* __restrict__ k,
    float* __restrict__ v, float* __restrict__ s) {
    __shared__ float xs[RB][HID];
    int n0 = blockIdx.x * RB;
    int t = threadIdx.x;
    for (int i = t; i < RB * HID; i += 256) {
        int r = i >> 6, d = i & 63;
        int n = n0 + r;
        xs[r][d] = (n < N_NODES) ? x[n * HID + d] : 0.f;
    }
    __syncthreads();
    int m = t >> 6, c = t & 63;
    const float* W = (m == 0) ? Wq : (m == 1) ? Wk : (m == 2) ? Wv : Ws;
    const float* B = (m == 0) ? bq : (m == 1) ? bk : (m == 2) ? bv : bs;
    float acc[RB];
#pragma unroll
    for (int r = 0; r < RB; ++r) acc[r] = 0.f;
    for (int i = 0; i < HID; ++i) {
        float w = W[i * HID + c];
#pragma unroll
        for (int r = 0; r < RB; ++r) acc[r] += xs[r][i] * w;
    }
    float b = B[c];
    float* out = (m == 0) ? q : (m == 1) ? k : (m == 2) ? v : s;
#pragma unroll
    for (int r = 0; r < RB; ++r) {
        int n = n0 + r;
        if (n < N_NODES) out[n * HID + c] = acc[r] + b;
    }
}

// ---------------- per-node attention aggregation + skip + LN/ReLU; 1 wave per node
__global__ __launch_bounds__(256) void k_agg(
    const float* __restrict__ q, const float* __restrict__ k,
    const float* __restrict__ v, const float* __restrict__ skip,
    const float* __restrict__ ef, const int* __restrict__ src_sorted,
    const int* __restrict__ rowptr, const float* __restrict__ Wedge,
    const float* __restrict__ ln_g, const float* __restrict__ ln_b,
    float* __restrict__ xout, int do_ln) {
    __shared__ float we[EDGE_DIM * HID];  // 4 KB
    int t = threadIdx.x;
    for (int i = t; i < EDGE_DIM * HID; i += 256) we[i] = Wedge[i];
    __syncthreads();
    int wid = t >> 6, lane = t & 63;
    int n = blockIdx.x * 4 + wid;
    if (n >= N_NODES) return;
    float qd = q[n * HID + lane];
    int rs = rowptr[n], re = rowptr[n + 1];
    float m = -1e30f, lsum = 0.f, acc = 0.f;
    const float scale = 0.35355339059327373f;  // 1/sqrt(8)
    for (int j = rs; j < re; ++j) {
        int s = src_sorted[j];
        const float* efr = ef + (size_t)j * EDGE_DIM;
        float ed = 0.f;
#pragma unroll
        for (int i = 0; i < EDGE_DIM; ++i) ed += efr[i] * we[i * HID + lane];
        float kj = k[s * HID + lane] + ed;
        float p = qd * kj;
        p += __shfl_xor(p, 1);
        p += __shfl_xor(p, 2);
        p += __shfl_xor(p, 4);
        float alpha = p * scale;
        float nm = fmaxf(m, alpha);
        float corr = expf(m - nm);
        float pa = expf(alpha - nm);
        float vd = v[s * HID + lane] + ed;
        lsum = lsum * corr + pa;
        acc = acc * corr + pa * vd;
        m = nm;
    }
    float out = acc / (lsum + 1e-16f) + skip[n * HID + lane];
    if (do_ln) {
        float ssum = out;
#pragma unroll
        for (int o = 1; o < 64; o <<= 1) ssum += __shfl_xor(ssum, o);
        float mu = ssum * (1.f / 64.f);
        float dv = out - mu;
        float vs = dv * dv;
#pragma unroll
        for (int o = 1; o < 64; o <<= 1) vs += __shfl_xor(vs, o);
        float var = vs * (1.f / 64.f);
        float y = ln_g[lane] * dv / sqrtf(var + EPS) + ln_b[lane];
        out = fmaxf(y, 0.f);
    }
    xout[n * HID + lane] = out;
}

// ---------------- policy head: out[n*2+c] = x[n]·Wp[:,c] + bp[c]
__global__ __launch_bounds__(256) void k_policy(
    const float* __restrict__ x, const float* __restrict__ Wp,
    const float* __restrict__ bp, float* __restrict__ out) {
    int t = threadIdx.x;
    int wid = t >> 6, lane = t & 63;
    int n = blockIdx.x * 4 + wid;
    if (n >= N_NODES) return;
    float xd = x[n * HID + lane];
    float p0 = xd * Wp[lane * 2 + 0];
    float p1 = xd * Wp[lane * 2 + 1];
#pragma unroll
    for (int o = 1; o < 64; o <<= 1) {
        p0 += __shfl_xor(p0, o);
        p1 += __shfl_xor(p1, o);
    }
    if (lane == 0) {
        out[n * 2 + 0] = p0 + bp[0];
        out[n * 2 + 1] = p1 + bp[1];
    }
}

// ---------------- column sums for the graph mean
__global__ __launch_bounds__(256) void k_colsum(const float* __restrict__ x, float* __restrict__ gsum) {
    __shared__ float sh[256];
    int t = threadIdx.x;
    int col = t & 63;
    float acc = 0.f;
    for (int n = blockIdx.x * 4 + (t >> 6); n < N_NODES; n += gridDim.x * 4)
        acc += x[n * HID + col];
    sh[t] = acc;
    __syncthreads();
    if (t < 64) {
        float s = sh[t] + sh[t + 64] + sh[t + 128] + sh[t + 192];
        atomicAdd(&gsum[t], s);
    }
}

// ---------------- value head (single wave)
__global__ __launch_bounds__(64) void k_value(
    const float* __restrict__ gsum, const float* __restrict__ Wv1,
    const float* __restrict__ bv1, const float* __restrict__ Wv2,
    const float* __restrict__ bv2, float* __restrict__ out) {
    int lane = threadIdx.x;
    float h = bv1[lane];
    for (int i = 0; i < HID; ++i) h += (gsum[i] * (1.f / N_NODES)) * Wv1[i * HID + lane];
    h = fmaxf(h, 0.f);
    float p = h * Wv2[lane];
#pragma unroll
    for (int o = 1; o < 64; o <<= 1) p += __shfl_xor(p, o);
    if (lane == 0) out[0] = tanhf(p + bv2[0]);
}

extern "C" void kernel_launch(void* const* d_in, const int* in_sizes, int n_in,
                              void* d_out, int out_size, void* d_ws, size_t ws_size,
                              hipStream_t stream) {
    const int* x_nodes = (const int*)d_in[0];
    const int* edge_index = (const int*)d_in[1];
    const int* edge_label = (const int*)d_in[2];
    const int* edge_sign = (const int*)d_in[3];
    const float* emb_strand = (const float*)d_in[4];
    const float* emb_pos = (const float*)d_in[5];
    const float* emb_sign = (const float*)d_in[6];
    const float* We = (const float*)d_in[7];
    const float* be = (const float*)d_in[8];
    const float* Wq = (const float*)d_in[9];
    const float* bq = (const float*)d_in[10];
    const float* Wk = (const float*)d_in[11];
    const float* bk = (const float*)d_in[12];
    const float* Wv = (const float*)d_in[13];
    const float* bv = (const float*)d_in[14];
    const float* Wedge = (const float*)d_in[15];
    const float* Wskip = (const float*)d_in[16];
    const float* bskip = (const float*)d_in[17];
    const float* ln_g = (const float*)d_in[18];
    const float* ln_b = (const float*)d_in[19];
    const float* Wp = (const float*)d_in[20];
    const float* bp = (const float*)d_in[21];
    const float* Wv1 = (const float*)d_in[22];
    const float* bv1 = (const float*)d_in[23];
    const float* Wv2 = (const float*)d_in[24];
    const float* bv2 = (const float*)d_in[25];
    float* out = (float*)d_out;

    const int* src = edge_index;            // row 0
    const int* dst = edge_index + N_EDGES;  // row 1

    char* ws = (char*)d_ws;
    size_t off = 0;
    auto alloc = [&](size_t bytes) -> void* {
        void* p = ws + off;
        off += (bytes + 255) & ~(size_t)255;
        return p;
    };
    float* x = (float*)alloc((size_t)N_NODES * HID * 4);
    float* q = (float*)alloc((size_t)N_NODES * HID * 4);
    float* k = (float*)alloc((size_t)N_NODES * HID * 4);
    float* v = (float*)alloc((size_t)N_NODES * HID * 4);
    float* sk = (float*)alloc((size_t)N_NODES * HID * 4);
    float* ef = (float*)alloc((size_t)N_EDGES * EDGE_DIM * 4);
    int* src_sorted = (int*)alloc((size_t)N_EDGES * 4);
    int* eorig = (int*)alloc((size_t)N_EDGES * 4);
    int* rowptr = (int*)alloc((size_t)(N_NODES + 1) * 4);
    int* cnt = (int*)alloc((size_t)N_NODES * 4);
    int* cursor = (int*)alloc((size_t)N_NODES * 4);
    float* gsum = (float*)alloc(64 * 4);

    hipMemsetAsync(cnt, 0, (size_t)N_NODES * 4, stream);
    hipMemsetAsync(cursor, 0, (size_t)N_NODES * 4, stream);
    hipMemsetAsync(gsum, 0, 64 * 4, stream);

    // node features
    k_node_feat<<<(N_NODES * HID + 255) / 256, 256, 0, stream>>>(x_nodes, emb_strand, emb_pos, x);
    // CSR
    k_count<<<(N_EDGES + 255) / 256, 256, 0, stream>>>(dst, cnt);
    k_scan<<<1, 1024, 0, stream>>>(cnt, rowptr);
    k_fill<<<(N_EDGES + 255) / 256, 256, 0, stream>>>(src, dst, rowptr, cursor, src_sorted, eorig);
    // edge features (sorted order)
    k_ef<<<(N_EDGES * EDGE_DIM + 255) / 256, 256, 0, stream>>>(
        eorig, edge_label, edge_sign, emb_strand, emb_sign, We, be, ef);

    for (int l = 0; l < LAYERS; ++l) {
        k_qkvs<<<(N_NODES + RB - 1) / RB, 256, 0, stream>>>(
            x,
            Wq + (size_t)l * HID * HID, bq + (size_t)l * HID,
            Wk + (size_t)l * HID * HID, bk + (size_t)l * HID,
            Wv + (size_t)l * HID * HID, bv + (size_t)l * HID,
            Wskip + (size_t)l * HID * HID, bskip + (size_t)l * HID,
            q, k, v, sk);
        int do_ln = (l < LAYERS - 1) ? 1 : 0;
        const float* lg = do_ln ? (ln_g + (size_t)l * HID) : ln_g;
        const float* lb = do_ln ? (ln_b + (size_t)l * HID) : ln_b;
        k_agg<<<(N_NODES + 3) / 4, 256, 0, stream>>>(
            q, k, v, sk, ef, src_sorted, rowptr,
            Wedge + (size_t)l * EDGE_DIM * HID, lg, lb, x, do_ln);
    }

    // heads
    k_policy<<<(N_NODES + 3) / 4, 256, 0, stream>>>(x, Wp, bp, out);
    k_colsum<<<128, 256, 0, stream>>>(x, gsum);
    k_value<<<1, 64, 0, stream>>>(gsum, Wv1, bv1, Wv2, bv2, out + 2 * N_NODES);
}

// Round 2
// 872.934 us; speedup vs baseline: 1.6883x; 1.6883x over previous
//
#include <hip/hip_runtime.h>
#include <math.h>

#define N_NODES 50000
#define N_EDGES 800000
#define HID 64
#define HEADS 8
#define DH 8
#define LAYERS 6
#define EDGE_DIM 16
#define SIGN_DIM 8
#define NSIGN 3
#define VOC 512
#define NCOMB (VOC * NSIGN)  // 1536 distinct (label, sign) pairs
#define EPS 1e-5f

// ---------------- node features: x[n][d] = sum_slot (emb_strand[xn[n][slot]][d] + emb_pos[slot][d])
__global__ __launch_bounds__(256) void k_node_feat(
    const int* __restrict__ xn, const float* __restrict__ emb_s,
    const float* __restrict__ emb_p, float* __restrict__ x) {
    int idx = blockIdx.x * 256 + threadIdx.x;  // n*64+d
    if (idx >= N_NODES * HID) return;
    int n = idx >> 6, d = idx & 63;
    float acc = 0.f;
#pragma unroll
    for (int s = 0; s < 4; ++s) {
        int id = xn[n * 4 + s];
        acc += emb_s[id * HID + d] + emb_p[s * HID + d];
    }
    x[idx] = acc;
}

// ---------------- ef table: T[comb][c] = [strand_emb(lb) | sign_emb(sg)] @ We + be
__global__ __launch_bounds__(256) void k_tab1(
    const float* __restrict__ emb_s, const float* __restrict__ emb_sg,
    const float* __restrict__ We, const float* __restrict__ be,
    float* __restrict__ T) {
    int gid = blockIdx.x * 256 + threadIdx.x;  // comb*16+c
    int comb = gid >> 4, c = gid & 15;
    if (comb >= NCOMB) return;
    int lb = comb / NSIGN, sg = comb % NSIGN;
    float acc = be[c];
    const float* er = emb_s + lb * HID;
#pragma unroll
    for (int j = 0; j < HID; ++j) acc += er[j] * We[j * EDGE_DIM + c];
    const float* sr = emb_sg + sg * SIGN_DIM;
#pragma unroll
    for (int j = 0; j < SIGN_DIM; ++j) acc += sr[j] * We[(HID + j) * EDGE_DIM + c];
    T[comb * EDGE_DIM + c] = acc;
}

// ---------------- per-layer edge-contribution table: TE[l][comb][d] = T[comb] @ Wedge[l]
__global__ __launch_bounds__(256) void k_tab2(
    const float* __restrict__ T, const float* __restrict__ Wedge,
    float* __restrict__ TE) {
    int idx = blockIdx.x * 256 + threadIdx.x;  // l*NCOMB*64 + comb*64 + d
    if (idx >= LAYERS * NCOMB * HID) return;
    int l = idx / (NCOMB * HID);
    int r = idx - l * (NCOMB * HID);
    int comb = r >> 6, d = r & 63;
    const float* tr = T + comb * EDGE_DIM;
    const float* w = Wedge + l * EDGE_DIM * HID;
    float acc = 0.f;
#pragma unroll
    for (int j = 0; j < EDGE_DIM; ++j) acc += tr[j] * w[j * HID + d];
    TE[idx] = acc;
}

// ---------------- CSR build
__global__ __launch_bounds__(256) void k_count(const int* __restrict__ dst, int* __restrict__ cnt) {
    int e = blockIdx.x * 256 + threadIdx.x;
    if (e < N_EDGES) atomicAdd(&cnt[dst[e]], 1);
}

__global__ __launch_bounds__(1024) void k_scan(const int* __restrict__ cnt, int* __restrict__ rowptr) {
    __shared__ int wsum[16];
    __shared__ int sbase;
    int t = threadIdx.x;
    int lane = t & 63, w = t >> 6;
    if (t == 0) { sbase = 0; rowptr[0] = 0; }
    __syncthreads();
    for (int start = 0; start < N_NODES; start += 1024) {
        int i = start + t;
        int val = (i < N_NODES) ? cnt[i] : 0;
        int incl = val;
#pragma unroll
        for (int o = 1; o < 64; o <<= 1) {
            int u = __shfl_up(incl, o);
            if (lane >= o) incl += u;
        }
        if (lane == 63) wsum[w] = incl;
        __syncthreads();
        int woff = 0;
        for (int j = 0; j < w; ++j) woff += wsum[j];
        int g = sbase + woff + incl;
        if (i < N_NODES) rowptr[i + 1] = g;
        __syncthreads();
        if (t == 1023) sbase = g;
        __syncthreads();
    }
}

// fill: scomb[idx] = {src, label*3+sign} in dst-sorted order
__global__ __launch_bounds__(256) void k_fill(
    const int* __restrict__ src, const int* __restrict__ dst,
    const int* __restrict__ label, const int* __restrict__ sign,
    const int* __restrict__ rowptr, int* __restrict__ cursor,
    int2* __restrict__ scomb) {
    int e = blockIdx.x * 256 + threadIdx.x;
    if (e >= N_EDGES) return;
    int d = dst[e];
    int pos = atomicAdd(&cursor[d], 1);
    int idx = rowptr[d] + pos;
    scomb[idx] = make_int2(src[e], label[e] * NSIGN + sign[e]);
}

// ---------------- fused q/k/v/skip projection: 16 nodes per 256-thread block
#define RB 16
__global__ __launch_bounds__(256) void k_qkvs(
    const float* __restrict__ x,
    const float* __restrict__ Wq, const float* __restrict__ bq,
    const float* __restrict__ Wk, const float* __restrict__ bk,
    const float* __restrict__ Wv, const float* __restrict__ bv,
    const float* __restrict__ Ws, const float* __restrict__ bs,
    float* __restrict__ q, float* __restrict__ k,
    float* __restrict__ v, float* __restrict__ s) {
    __shared__ float xs[RB][HID];
    int n0 = blockIdx.x * RB;
    int t = threadIdx.x;
    for (int i = t; i < RB * HID; i += 256) {
        int r = i >> 6, d = i & 63;
        int n = n0 + r;
        xs[r][d] = (n < N_NODES) ? x[n * HID + d] : 0.f;
    }
    __syncthreads();
    int m = t >> 6, c = t & 63;
    const float* W = (m == 0) ? Wq : (m == 1) ? Wk : (m == 2) ? Wv : Ws;
    const float* B = (m == 0) ? bq : (m == 1) ? bk : (m == 2) ? bv : bs;
    float acc[RB];
#pragma unroll
    for (int r = 0; r < RB; ++r) acc[r] = 0.f;
    for (int i = 0; i < HID; ++i) {
        float w = W[i * HID + c];
#pragma unroll
        for (int r = 0; r < RB; ++r) acc[r] += xs[r][i] * w;
    }
    float b = B[c];
    float* out = (m == 0) ? q : (m == 1) ? k : (m == 2) ? v : s;
#pragma unroll
    for (int r = 0; r < RB; ++r) {
        int n = n0 + r;
        if (n < N_NODES) out[n * HID + c] = acc[r] + b;
    }
}

// ---------------- per-node attention aggregation + skip + LN/ReLU (+ fused policy on last layer)
__global__ __launch_bounds__(256) void k_agg(
    const float* __restrict__ q, const float* __restrict__ kk,
    const float* __restrict__ vv, const float* __restrict__ skip,
    const float* __restrict__ te, const int2* __restrict__ scomb,
    const int* __restrict__ rowptr,
    const float* __restrict__ ln_g, const float* __restrict__ ln_b,
    float* __restrict__ xout, int do_ln,
    const float* __restrict__ Wp, const float* __restrict__ bp,
    float* __restrict__ pol) {
    int t = threadIdx.x;
    int wid = t >> 6, lane = t & 63;
    int n = blockIdx.x * 4 + wid;
    if (n >= N_NODES) return;
    float qd = q[(n << 6) + lane];
    int rs = rowptr[n], re = rowptr[n + 1];
    float m = -1e30f, lsum = 0.f, acc = 0.f;
    const float scale = 0.35355339059327373f;  // 1/sqrt(8)
    int j = rs;
    if ((re - rs) & 1) {
        int2 e0 = scomb[j];
        float t0 = te[(e0.y << 6) + lane];
        float k0 = kk[(e0.x << 6) + lane];
        float v0 = vv[(e0.x << 6) + lane];
        float p0 = qd * (k0 + t0);
        p0 += __shfl_xor(p0, 1);
        p0 += __shfl_xor(p0, 2);
        p0 += __shfl_xor(p0, 4);
        float a0 = p0 * scale;
        m = a0;
        lsum = 1.f;
        acc = v0 + t0;
        ++j;
    }
    for (; j < re; j += 2) {
        int2 e0 = scomb[j], e1 = scomb[j + 1];
        float t0 = te[(e0.y << 6) + lane];
        float k0 = kk[(e0.x << 6) + lane];
        float v0 = vv[(e0.x << 6) + lane];
        float t1 = te[(e1.y << 6) + lane];
        float k1 = kk[(e1.x << 6) + lane];
        float v1 = vv[(e1.x << 6) + lane];
        float p0 = qd * (k0 + t0);
        p0 += __shfl_xor(p0, 1);
        p0 += __shfl_xor(p0, 2);
        p0 += __shfl_xor(p0, 4);
        float p1 = qd * (k1 + t1);
        p1 += __shfl_xor(p1, 1);
        p1 += __shfl_xor(p1, 2);
        p1 += __shfl_xor(p1, 4);
        float a0 = p0 * scale, a1 = p1 * scale;
        float nm = fmaxf(m, fmaxf(a0, a1));
        float c = __expf(m - nm);
        float w0 = __expf(a0 - nm);
        float w1 = __expf(a1 - nm);
        lsum = lsum * c + w0 + w1;
        acc = acc * c + w0 * (v0 + t0) + w1 * (v1 + t1);
        m = nm;
    }
    float outv = acc / (lsum + 1e-16f) + skip[(n << 6) + lane];
    if (do_ln) {
        float ssum = outv;
#pragma unroll
        for (int o = 1; o < 64; o <<= 1) ssum += __shfl_xor(ssum, o);
        float mu = ssum * (1.f / 64.f);
        float dv = outv - mu;
        float vs = dv * dv;
#pragma unroll
        for (int o = 1; o < 64; o <<= 1) vs += __shfl_xor(vs, o);
        float var = vs * (1.f / 64.f);
        float y = ln_g[lane] * dv / sqrtf(var + EPS) + ln_b[lane];
        outv = fmaxf(y, 0.f);
        xout[(n << 6) + lane] = outv;
    } else {
        xout[(n << 6) + lane] = outv;
        // fused policy head
        float p0 = outv * Wp[lane * 2 + 0];
        float p1 = outv * Wp[lane * 2 + 1];
#pragma unroll
        for (int o = 1; o < 64; o <<= 1) {
            p0 += __shfl_xor(p0, o);
            p1 += __shfl_xor(p1, o);
        }
        if (lane == 0) {
            pol[n * 2 + 0] = p0 + bp[0];
            pol[n * 2 + 1] = p1 + bp[1];
        }
    }
}

// ---------------- column sums for the graph mean
__global__ __launch_bounds__(256) void k_colsum(const float* __restrict__ x, float* __restrict__ gsum) {
    __shared__ float sh[256];
    int t = threadIdx.x;
    int col = t & 63;
    float acc = 0.f;
    for (int n = blockIdx.x * 4 + (t >> 6); n < N_NODES; n += gridDim.x * 4)
        acc += x[n * HID + col];
    sh[t] = acc;
    __syncthreads();
    if (t < 64) {
        float s = sh[t] + sh[t + 64] + sh[t + 128] + sh[t + 192];
        atomicAdd(&gsum[t], s);
    }
}

// ---------------- value head (single wave)
__global__ __launch_bounds__(64) void k_value(
    const float* __restrict__ gsum, const float* __restrict__ Wv1,
    const float* __restrict__ bv1, const float* __restrict__ Wv2,
    const float* __restrict__ bv2, float* __restrict__ out) {
    int lane = threadIdx.x;
    float h = bv1[lane];
    for (int i = 0; i < HID; ++i) h += (gsum[i] * (1.f / N_NODES)) * Wv1[i * HID + lane];
    h = fmaxf(h, 0.f);
    float p = h * Wv2[lane];
#pragma unroll
    for (int o = 1; o < 64; o <<= 1) p += __shfl_xor(p, o);
    if (lane == 0) out[0] = tanhf(p + bv2[0]);
}

extern "C" void kernel_launch(void* const* d_in, const int* in_sizes, int n_in,
                              void* d_out, int out_size, void* d_ws, size_t ws_size,
                              hipStream_t stream) {
    const int* x_nodes = (const int*)d_in[0];
    const int* edge_index = (const int*)d_in[1];
    const int* edge_label = (const int*)d_in[2];
    const int* edge_sign = (const int*)d_in[3];
    const float* emb_strand = (const float*)d_in[4];
    const float* emb_pos = (const float*)d_in[5];
    const float* emb_sign = (const float*)d_in[6];
    const float* We = (const float*)d_in[7];
    const float* be = (const float*)d_in[8];
    const float* Wq = (const float*)d_in[9];
    const float* bq = (const float*)d_in[10];
    const float* Wk = (const float*)d_in[11];
    const float* bk = (const float*)d_in[12];
    const float* Wv = (const float*)d_in[13];
    const float* bv = (const float*)d_in[14];
    const float* Wedge = (const float*)d_in[15];
    const float* Wskip = (const float*)d_in[16];
    const float* bskip = (const float*)d_in[17];
    const float* ln_g = (const float*)d_in[18];
    const float* ln_b = (const float*)d_in[19];
    const float* Wp = (const float*)d_in[20];
    const float* bp = (const float*)d_in[21];
    const float* Wv1 = (const float*)d_in[22];
    const float* bv1 = (const float*)d_in[23];
    const float* Wv2 = (const float*)d_in[24];
    const float* bv2 = (const float*)d_in[25];
    float* out = (float*)d_out;

    const int* src = edge_index;            // row 0
    const int* dst = edge_index + N_EDGES;  // row 1

    char* ws = (char*)d_ws;
    size_t off = 0;
    auto alloc = [&](size_t bytes) -> void* {
        void* p = ws + off;
        off += (bytes + 255) & ~(size_t)255;
        return p;
    };
    float* x = (float*)alloc((size_t)N_NODES * HID * 4);
    float* q = (float*)alloc((size_t)N_NODES * HID * 4);
    float* k = (float*)alloc((size_t)N_NODES * HID * 4);
    float* v = (float*)alloc((size_t)N_NODES * HID * 4);
    float* sk = (float*)alloc((size_t)N_NODES * HID * 4);
    int2* scomb = (int2*)alloc((size_t)N_EDGES * 8);
    int* rowptr = (int*)alloc((size_t)(N_NODES + 1) * 4);
    int* cnt = (int*)alloc((size_t)N_NODES * 4);
    int* cursor = (int*)alloc((size_t)N_NODES * 4);
    float* T = (float*)alloc((size_t)NCOMB * EDGE_DIM * 4);
    float* TE = (float*)alloc((size_t)LAYERS * NCOMB * HID * 4);
    float* gsum = (float*)alloc(64 * 4);

    hipMemsetAsync(cnt, 0, (size_t)N_NODES * 4, stream);
    hipMemsetAsync(cursor, 0, (size_t)N_NODES * 4, stream);
    hipMemsetAsync(gsum, 0, 64 * 4, stream);

    // node features + edge tables
    k_node_feat<<<(N_NODES * HID + 255) / 256, 256, 0, stream>>>(x_nodes, emb_strand, emb_pos, x);
    k_tab1<<<(NCOMB * EDGE_DIM + 255) / 256, 256, 0, stream>>>(emb_strand, emb_sign, We, be, T);
    k_tab2<<<(LAYERS * NCOMB * HID + 255) / 256, 256, 0, stream>>>(T, Wedge, TE);
    // CSR
    k_count<<<(N_EDGES + 255) / 256, 256, 0, stream>>>(dst, cnt);
    k_scan<<<1, 1024, 0, stream>>>(cnt, rowptr);
    k_fill<<<(N_EDGES + 255) / 256, 256, 0, stream>>>(src, dst, edge_label, edge_sign,
                                                      rowptr, cursor, scomb);

    for (int l = 0; l < LAYERS; ++l) {
        k_qkvs<<<(N_NODES + RB - 1) / RB, 256, 0, stream>>>(
            x,
            Wq + (size_t)l * HID * HID, bq + (size_t)l * HID,
            Wk + (size_t)l * HID * HID, bk + (size_t)l * HID,
            Wv + (size_t)l * HID * HID, bv + (size_t)l * HID,
            Wskip + (size_t)l * HID * HID, bskip + (size_t)l * HID,
            q, k, v, sk);
        int do_ln = (l < LAYERS - 1) ? 1 : 0;
        const float* lg = do_ln ? (ln_g + (size_t)l * HID) : ln_g;
        const float* lb = do_ln ? (ln_b + (size_t)l * HID) : ln_b;
        k_agg<<<(N_NODES + 3) / 4, 256, 0, stream>>>(
            q, k, v, sk, TE + (size_t)l * NCOMB * HID, scomb, rowptr,
            lg, lb, x, do_ln, Wp, bp, out);
    }

    // heads
    k_colsum<<<128, 256, 0, stream>>>(x, gsum);
    k_value<<<1, 64, 0, stream>>>(gsum, Wv1, bv1, Wv2, bv2, out + 2 * N_NODES);
}

// Round 3
// 682.230 us; speedup vs baseline: 2.1603x; 1.2795x over previous
//
#include <hip/hip_runtime.h>
#include <math.h>

typedef _Float16 f16;
typedef _Float16 f16x8 __attribute__((ext_vector_type(8)));
typedef float f32x4 __attribute__((ext_vector_type(4)));

#define N_NODES 50000
#define N_EDGES 800000
#define HID 64
#define HEADS 8
#define DH 8
#define LAYERS 6
#define EDGE_DIM 16
#define SIGN_DIM 8
#define NSIGN 3
#define VOC 512
#define NCOMB (VOC * NSIGN)  // 1536 distinct (label, sign) pairs
#define EPS 1e-5f
#define SCAN_NBLK ((N_NODES + 1023) / 1024)

// ---------------- node features -> fp16: x16[n][d] = sum_slot (emb_strand[...] + emb_pos[...])
__global__ __launch_bounds__(256) void k_node_feat(
    const int* __restrict__ xn, const float* __restrict__ emb_s,
    const float* __restrict__ emb_p, f16* __restrict__ x16) {
    int idx = blockIdx.x * 256 + threadIdx.x;  // n*64+d
    if (idx >= N_NODES * HID) return;
    int n = idx >> 6, d = idx & 63;
    float acc = 0.f;
#pragma unroll
    for (int s = 0; s < 4; ++s) {
        int id = xn[n * 4 + s];
        acc += emb_s[id * HID + d] + emb_p[s * HID + d];
    }
    x16[idx] = (f16)acc;
}

// ---------------- ef table: T[comb][c] = [strand_emb(lb) | sign_emb(sg)] @ We + be
__global__ __launch_bounds__(256) void k_tab1(
    const float* __restrict__ emb_s, const float* __restrict__ emb_sg,
    const float* __restrict__ We, const float* __restrict__ be,
    float* __restrict__ T) {
    int gid = blockIdx.x * 256 + threadIdx.x;  // comb*16+c
    int comb = gid >> 4, c = gid & 15;
    if (comb >= NCOMB) return;
    int lb = comb / NSIGN, sg = comb % NSIGN;
    float acc = be[c];
    const float* er = emb_s + lb * HID;
#pragma unroll
    for (int j = 0; j < HID; ++j) acc += er[j] * We[j * EDGE_DIM + c];
    const float* sr = emb_sg + sg * SIGN_DIM;
#pragma unroll
    for (int j = 0; j < SIGN_DIM; ++j) acc += sr[j] * We[(HID + j) * EDGE_DIM + c];
    T[comb * EDGE_DIM + c] = acc;
}

// ---------------- per-layer edge-contribution table (fp16): TE[l][comb][d] = T[comb] @ Wedge[l]
__global__ __launch_bounds__(256) void k_tab2(
    const float* __restrict__ T, const float* __restrict__ Wedge,
    f16* __restrict__ TE) {
    int idx = blockIdx.x * 256 + threadIdx.x;  // l*NCOMB*64 + comb*64 + d
    if (idx >= LAYERS * NCOMB * HID) return;
    int l = idx / (NCOMB * HID);
    int r = idx - l * (NCOMB * HID);
    int comb = r >> 6, d = r & 63;
    const float* tr = T + comb * EDGE_DIM;
    const float* w = Wedge + l * EDGE_DIM * HID;
    float acc = 0.f;
#pragma unroll
    for (int j = 0; j < EDGE_DIM; ++j) acc += tr[j] * w[j * HID + d];
    TE[idx] = (f16)acc;
}

// ---------------- weight prep: WcatT[l][c][k] (fp16, col-major) and bcat[l][c] (fp32)
// col c: 0-63 = q, 64-127 = k, 128-191 = v, 192-255 = skip
__global__ __launch_bounds__(256) void k_wprep(
    const float* __restrict__ Wq, const float* __restrict__ bq,
    const float* __restrict__ Wk, const float* __restrict__ bk,
    const float* __restrict__ Wv, const float* __restrict__ bv,
    const float* __restrict__ Ws, const float* __restrict__ bs,
    f16* __restrict__ wcatT, float* __restrict__ bcat) {
    int idx = blockIdx.x * 256 + threadIdx.x;  // l*16384 + c*64 + kk
    if (idx >= LAYERS * 256 * HID) return;
    int l = idx >> 14;
    int r = idx & 16383;
    int c = r >> 6, kk = r & 63;
    int m = c >> 6, cc = c & 63;
    const float* W = (m == 0) ? Wq : (m == 1) ? Wk : (m == 2) ? Wv : Ws;
    wcatT[idx] = (f16)W[l * 4096 + kk * 64 + cc];
    if (kk == 0) {
        const float* B = (m == 0) ? bq : (m == 1) ? bk : (m == 2) ? bv : bs;
        bcat[l * 256 + c] = B[l * 64 + cc];
    }
}

// ---------------- CSR build
__global__ __launch_bounds__(256) void k_count(const int* __restrict__ dst, int* __restrict__ cnt) {
    int e = blockIdx.x * 256 + threadIdx.x;
    if (e < N_EDGES) atomicAdd(&cnt[dst[e]], 1);
}

// two-level scan: per-block inclusive scan + block sums
__global__ __launch_bounds__(1024) void k_scan1(
    const int* __restrict__ cnt, int* __restrict__ rowptr, int* __restrict__ bsum) {
    __shared__ int wsum[16];
    int t = threadIdx.x;
    int lane = t & 63, w = t >> 6;
    int i = blockIdx.x * 1024 + t;
    int val = (i < N_NODES) ? cnt[i] : 0;
    int incl = val;
#pragma unroll
    for (int o = 1; o < 64; o <<= 1) {
        int u = __shfl_up(incl, o);
        if (lane >= o) incl += u;
    }
    if (lane == 63) wsum[w] = incl;
    __syncthreads();
    int woff = 0;
    for (int j = 0; j < w; ++j) woff += wsum[j];
    int g = woff + incl;
    if (i < N_NODES) rowptr[i + 1] = g;
    if (t == 1023) bsum[blockIdx.x] = g;
}

__global__ __launch_bounds__(64) void k_scan2(int* __restrict__ bsum, int* __restrict__ boff) {
    int l = threadIdx.x;
    int v = (l < SCAN_NBLK) ? bsum[l] : 0;
    int incl = v;
#pragma unroll
    for (int o = 1; o < 64; o <<= 1) {
        int u = __shfl_up(incl, o);
        if (l >= o) incl += u;
    }
    if (l < SCAN_NBLK) boff[l] = incl - v;  // exclusive
}

__global__ __launch_bounds__(1024) void k_scan3(int* __restrict__ rowptr, const int* __restrict__ boff) {
    int i = blockIdx.x * 1024 + threadIdx.x;
    if (i < N_NODES) rowptr[i + 1] += boff[blockIdx.x];
    if (i == 0) rowptr[0] = 0;
}

// fill: scomb[idx] = {src, label*3+sign} in dst-sorted order
__global__ __launch_bounds__(256) void k_fill(
    const int* __restrict__ src, const int* __restrict__ dst,
    const int* __restrict__ label, const int* __restrict__ sign,
    const int* __restrict__ rowptr, int* __restrict__ cursor,
    int2* __restrict__ scomb) {
    int e = blockIdx.x * 256 + threadIdx.x;
    if (e >= N_EDGES) return;
    int d = dst[e];
    int pos = atomicAdd(&cursor[d], 1);
    int idx = rowptr[d] + pos;
    scomb[idx] = make_int2(src[e], label[e] * NSIGN + sign[e]);
}

// ---------------- MFMA projection: y[n][0:256] = x16[n] @ Wcat + bcat  (fp16 out)
// 16 nodes per block, 4 waves; wave w covers cols [w*64, w*64+64)
__global__ __launch_bounds__(256) void k_proj(
    const f16* __restrict__ x16, const f16* __restrict__ wcatT_l,
    const float* __restrict__ bcat_l, f16* __restrict__ y) {
    int t = threadIdx.x;
    int w = t >> 6, l = t & 63;
    int n0 = blockIdx.x * 16;
    int rowA = n0 + (l & 15);
    int kb = l >> 4;  // k-block 0..3, 8 contiguous k each
    const f16* xr = x16 + (rowA << 6) + (kb << 3);
    f16x8 a0 = *(const f16x8*)(xr);
    f16x8 a1 = *(const f16x8*)(xr + 32);
    int c0 = w << 6;
    int rbase = n0 + ((l >> 4) << 2);
#pragma unroll
    for (int tt = 0; tt < 4; ++tt) {
        int cl = c0 + tt * 16 + (l & 15);
        const f16* wr = wcatT_l + (cl << 6) + (kb << 3);
        f16x8 b0 = *(const f16x8*)(wr);
        f16x8 b1 = *(const f16x8*)(wr + 32);
        f32x4 z = {0.f, 0.f, 0.f, 0.f};
        z = __builtin_amdgcn_mfma_f32_16x16x32_f16(a0, b0, z, 0, 0, 0);
        z = __builtin_amdgcn_mfma_f32_16x16x32_f16(a1, b1, z, 0, 0, 0);
        float bb = bcat_l[cl];
#pragma unroll
        for (int r = 0; r < 4; ++r)
            y[(size_t)(rbase + r) * 256 + cl] = (f16)(z[r] + bb);
    }
}

// ---------------- per-node attention aggregation + skip + LN/ReLU (+ fused policy on last layer)
// y record per node: [q(64) | k(64) | v(64) | skip(64)] fp16
__global__ __launch_bounds__(256) void k_agg(
    const f16* __restrict__ y, const f16* __restrict__ te,
    const int2* __restrict__ scomb, const int* __restrict__ rowptr,
    const float* __restrict__ ln_g, const float* __restrict__ ln_b,
    f16* __restrict__ xout, int do_ln,
    const float* __restrict__ Wp, const float* __restrict__ bp,
    float* __restrict__ pol) {
    int t = threadIdx.x;
    int wid = t >> 6, lane = t & 63;
    int n = blockIdx.x * 4 + wid;
    if (n >= N_NODES) return;
    const f16* yn = y + ((size_t)n << 8);
    float qd = (float)yn[lane];
    int rs = rowptr[n], re = rowptr[n + 1];
    float m = -1e30f, lsum = 0.f, acc = 0.f;
    const float scale = 0.35355339059327373f;  // 1/sqrt(8)
    int j = rs;
    if ((re - rs) & 1) {
        int2 e0 = scomb[j];
        const f16* ys = y + ((size_t)e0.x << 8);
        float t0 = (float)te[(e0.y << 6) + lane];
        float k0 = (float)ys[64 + lane];
        float v0 = (float)ys[128 + lane];
        float p0 = qd * (k0 + t0);
        p0 += __shfl_xor(p0, 1);
        p0 += __shfl_xor(p0, 2);
        p0 += __shfl_xor(p0, 4);
        m = p0 * scale;
        lsum = 1.f;
        acc = v0 + t0;
        ++j;
    }
    for (; j < re; j += 2) {
        int2 e0 = scomb[j], e1 = scomb[j + 1];
        const f16* ys0 = y + ((size_t)e0.x << 8);
        const f16* ys1 = y + ((size_t)e1.x << 8);
        float t0 = (float)te[(e0.y << 6) + lane];
        float k0 = (float)ys0[64 + lane];
        float v0 = (float)ys0[128 + lane];
        float t1 = (float)te[(e1.y << 6) + lane];
        float k1 = (float)ys1[64 + lane];
        float v1 = (float)ys1[128 + lane];
        float p0 = qd * (k0 + t0);
        p0 += __shfl_xor(p0, 1);
        p0 += __shfl_xor(p0, 2);
        p0 += __shfl_xor(p0, 4);
        float p1 = qd * (k1 + t1);
        p1 += __shfl_xor(p1, 1);
        p1 += __shfl_xor(p1, 2);
        p1 += __shfl_xor(p1, 4);
        float a0 = p0 * scale, a1 = p1 * scale;
        float nm = fmaxf(m, fmaxf(a0, a1));
        float c = __expf(m - nm);
        float w0 = __expf(a0 - nm);
        float w1 = __expf(a1 - nm);
        lsum = lsum * c + w0 + w1;
        acc = acc * c + w0 * (v0 + t0) + w1 * (v1 + t1);
        m = nm;
    }
    float outv = acc / (lsum + 1e-16f) + (float)yn[192 + lane];
    if (do_ln) {
        float ssum = outv;
#pragma unroll
        for (int o = 1; o < 64; o <<= 1) ssum += __shfl_xor(ssum, o);
        float mu = ssum * (1.f / 64.f);
        float dv = outv - mu;
        float vs = dv * dv;
#pragma unroll
        for (int o = 1; o < 64; o <<= 1) vs += __shfl_xor(vs, o);
        float var = vs * (1.f / 64.f);
        float yv = ln_g[lane] * dv / sqrtf(var + EPS) + ln_b[lane];
        outv = fmaxf(yv, 0.f);
        xout[(n << 6) + lane] = (f16)outv;
    } else {
        xout[(n << 6) + lane] = (f16)outv;
        float p0 = outv * Wp[lane * 2 + 0];
        float p1 = outv * Wp[lane * 2 + 1];
#pragma unroll
        for (int o = 1; o < 64; o <<= 1) {
            p0 += __shfl_xor(p0, o);
            p1 += __shfl_xor(p1, o);
        }
        if (lane == 0) {
            pol[n * 2 + 0] = p0 + bp[0];
            pol[n * 2 + 1] = p1 + bp[1];
        }
    }
}

// ---------------- column sums for the graph mean (fp16 x)
__global__ __launch_bounds__(256) void k_colsum(const f16* __restrict__ x16, float* __restrict__ gsum) {
    __shared__ float sh[256];
    int t = threadIdx.x;
    int col = t & 63;
    float acc = 0.f;
    for (int n = blockIdx.x * 4 + (t >> 6); n < N_NODES; n += gridDim.x * 4)
        acc += (float)x16[(n << 6) + col];
    sh[t] = acc;
    __syncthreads();
    if (t < 64) {
        float s = sh[t] + sh[t + 64] + sh[t + 128] + sh[t + 192];
        atomicAdd(&gsum[t], s);
    }
}

// ---------------- value head (single wave)
__global__ __launch_bounds__(64) void k_value(
    const float* __restrict__ gsum, const float* __restrict__ Wv1,
    const float* __restrict__ bv1, const float* __restrict__ Wv2,
    const float* __restrict__ bv2, float* __restrict__ out) {
    int lane = threadIdx.x;
    float h = bv1[lane];
    for (int i = 0; i < HID; ++i) h += (gsum[i] * (1.f / N_NODES)) * Wv1[i * HID + lane];
    h = fmaxf(h, 0.f);
    float p = h * Wv2[lane];
#pragma unroll
    for (int o = 1; o < 64; o <<= 1) p += __shfl_xor(p, o);
    if (lane == 0) out[0] = tanhf(p + bv2[0]);
}

extern "C" void kernel_launch(void* const* d_in, const int* in_sizes, int n_in,
                              void* d_out, int out_size, void* d_ws, size_t ws_size,
                              hipStream_t stream) {
    const int* x_nodes = (const int*)d_in[0];
    const int* edge_index = (const int*)d_in[1];
    const int* edge_label = (const int*)d_in[2];
    const int* edge_sign = (const int*)d_in[3];
    const float* emb_strand = (const float*)d_in[4];
    const float* emb_pos = (const float*)d_in[5];
    const float* emb_sign = (const float*)d_in[6];
    const float* We = (const float*)d_in[7];
    const float* be = (const float*)d_in[8];
    const float* Wq = (const float*)d_in[9];
    const float* bq = (const float*)d_in[10];
    const float* Wk = (const float*)d_in[11];
    const float* bk = (const float*)d_in[12];
    const float* Wv = (const float*)d_in[13];
    const float* bv = (const float*)d_in[14];
    const float* Wedge = (const float*)d_in[15];
    const float* Wskip = (const float*)d_in[16];
    const float* bskip = (const float*)d_in[17];
    const float* ln_g = (const float*)d_in[18];
    const float* ln_b = (const float*)d_in[19];
    const float* Wp = (const float*)d_in[20];
    const float* bp = (const float*)d_in[21];
    const float* Wv1 = (const float*)d_in[22];
    const float* bv1 = (const float*)d_in[23];
    const float* Wv2 = (const float*)d_in[24];
    const float* bv2 = (const float*)d_in[25];
    float* out = (float*)d_out;

    const int* src = edge_index;            // row 0
    const int* dst = edge_index + N_EDGES;  // row 1

    char* ws = (char*)d_ws;
    size_t off = 0;
    auto alloc = [&](size_t bytes) -> void* {
        void* p = ws + off;
        off += (bytes + 255) & ~(size_t)255;
        return p;
    };
    f16* x16 = (f16*)alloc((size_t)N_NODES * HID * 2);
    f16* y = (f16*)alloc((size_t)N_NODES * 256 * 2);
    int2* scomb = (int2*)alloc((size_t)N_EDGES * 8);
    int* rowptr = (int*)alloc((size_t)(N_NODES + 1) * 4);
    int* cnt = (int*)alloc((size_t)N_NODES * 4);
    int* cursor = (int*)alloc((size_t)N_NODES * 4);
    int* bsum = (int*)alloc((size_t)SCAN_NBLK * 4);
    int* boff = (int*)alloc((size_t)SCAN_NBLK * 4);
    float* T = (float*)alloc((size_t)NCOMB * EDGE_DIM * 4);
    f16* TE = (f16*)alloc((size_t)LAYERS * NCOMB * HID * 2);
    f16* wcatT = (f16*)alloc((size_t)LAYERS * 256 * HID * 2);
    float* bcat = (float*)alloc((size_t)LAYERS * 256 * 4);
    float* gsum = (float*)alloc(64 * 4);

    hipMemsetAsync(cnt, 0, (size_t)N_NODES * 4, stream);
    hipMemsetAsync(cursor, 0, (size_t)N_NODES * 4, stream);
    hipMemsetAsync(gsum, 0, 64 * 4, stream);

    // node features + tables + weight prep
    k_node_feat<<<(N_NODES * HID + 255) / 256, 256, 0, stream>>>(x_nodes, emb_strand, emb_pos, x16);
    k_tab1<<<(NCOMB * EDGE_DIM + 255) / 256, 256, 0, stream>>>(emb_strand, emb_sign, We, be, T);
    k_tab2<<<(LAYERS * NCOMB * HID + 255) / 256, 256, 0, stream>>>(T, Wedge, TE);
    k_wprep<<<(LAYERS * 256 * HID + 255) / 256, 256, 0, stream>>>(
        Wq, bq, Wk, bk, Wv, bv, Wskip, bskip, wcatT, bcat);
    // CSR
    k_count<<<(N_EDGES + 255) / 256, 256, 0, stream>>>(dst, cnt);
    k_scan1<<<SCAN_NBLK, 1024, 0, stream>>>(cnt, rowptr, bsum);
    k_scan2<<<1, 64, 0, stream>>>(bsum, boff);
    k_scan3<<<SCAN_NBLK, 1024, 0, stream>>>(rowptr, boff);
    k_fill<<<(N_EDGES + 255) / 256, 256, 0, stream>>>(src, dst, edge_label, edge_sign,
                                                      rowptr, cursor, scomb);

    for (int l = 0; l < LAYERS; ++l) {
        k_proj<<<N_NODES / 16, 256, 0, stream>>>(
            x16, wcatT + (size_t)l * 256 * HID, bcat + (size_t)l * 256, y);
        int do_ln = (l < LAYERS - 1) ? 1 : 0;
        const float* lg = do_ln ? (ln_g + (size_t)l * HID) : ln_g;
        const float* lb = do_ln ? (ln_b + (size_t)l * HID) : ln_b;
        k_agg<<<(N_NODES + 3) / 4, 256, 0, stream>>>(
            y, TE + (size_t)l * NCOMB * HID, scomb, rowptr,
            lg, lb, x16, do_ln, Wp, bp, out);
    }

    // heads
    k_colsum<<<128, 256, 0, stream>>>(x16, gsum);
    k_value<<<1, 64, 0, stream>>>(gsum, Wv1, bv1, Wv2, bv2, out + 2 * N_NODES);
}

// Round 4
// 513.136 us; speedup vs baseline: 2.8721x; 1.3295x over previous
//
#include <hip/hip_runtime.h>
#include <math.h>

typedef _Float16 f16;
typedef _Float16 f16x8 __attribute__((ext_vector_type(8)));
typedef _Float16 f16x2 __attribute__((ext_vector_type(2)));
typedef float f32x4 __attribute__((ext_vector_type(4)));

#define N_NODES 50000
#define N_EDGES 800000
#define HID 64
#define HEADS 8
#define DH 8
#define LAYERS 6
#define EDGE_DIM 16
#define SIGN_DIM 8
#define NSIGN 3
#define VOC 512
#define NCOMB (VOC * NSIGN)
#define EPS 1e-5f
#define SCAN_NBLK ((N_NODES + 1023) / 1024)

__device__ __forceinline__ float dot8(f16x8 a, f16x8 b, float c) {
#if __has_builtin(__builtin_amdgcn_fdot2)
    c = __builtin_amdgcn_fdot2(__builtin_shufflevector(a, a, 0, 1),
                               __builtin_shufflevector(b, b, 0, 1), c, false);
    c = __builtin_amdgcn_fdot2(__builtin_shufflevector(a, a, 2, 3),
                               __builtin_shufflevector(b, b, 2, 3), c, false);
    c = __builtin_amdgcn_fdot2(__builtin_shufflevector(a, a, 4, 5),
                               __builtin_shufflevector(b, b, 4, 5), c, false);
    c = __builtin_amdgcn_fdot2(__builtin_shufflevector(a, a, 6, 7),
                               __builtin_shufflevector(b, b, 6, 7), c, false);
#else
#pragma unroll
    for (int i = 0; i < 8; ++i) c += (float)a[i] * (float)b[i];
#endif
    return c;
}

// ---------------- node features -> fp16
__global__ __launch_bounds__(256) void k_node_feat(
    const int* __restrict__ xn, const float* __restrict__ emb_s,
    const float* __restrict__ emb_p, f16* __restrict__ x16) {
    int idx = blockIdx.x * 256 + threadIdx.x;
    if (idx >= N_NODES * HID) return;
    int n = idx >> 6, d = idx & 63;
    float acc = 0.f;
#pragma unroll
    for (int s = 0; s < 4; ++s) {
        int id = xn[n * 4 + s];
        acc += emb_s[id * HID + d] + emb_p[s * HID + d];
    }
    x16[idx] = (f16)acc;
}

// ---------------- ef table
__global__ __launch_bounds__(256) void k_tab1(
    const float* __restrict__ emb_s, const float* __restrict__ emb_sg,
    const float* __restrict__ We, const float* __restrict__ be,
    float* __restrict__ T) {
    int gid = blockIdx.x * 256 + threadIdx.x;
    int comb = gid >> 4, c = gid & 15;
    if (comb >= NCOMB) return;
    int lb = comb / NSIGN, sg = comb % NSIGN;
    float acc = be[c];
    const float* er = emb_s + lb * HID;
#pragma unroll
    for (int j = 0; j < HID; ++j) acc += er[j] * We[j * EDGE_DIM + c];
    const float* sr = emb_sg + sg * SIGN_DIM;
#pragma unroll
    for (int j = 0; j < SIGN_DIM; ++j) acc += sr[j] * We[(HID + j) * EDGE_DIM + c];
    T[comb * EDGE_DIM + c] = acc;
}

// ---------------- per-layer edge-contribution table (fp16)
__global__ __launch_bounds__(256) void k_tab2(
    const float* __restrict__ T, const float* __restrict__ Wedge,
    f16* __restrict__ TE) {
    int idx = blockIdx.x * 256 + threadIdx.x;
    if (idx >= LAYERS * NCOMB * HID) return;
    int l = idx / (NCOMB * HID);
    int r = idx - l * (NCOMB * HID);
    int comb = r >> 6, d = r & 63;
    const float* tr = T + comb * EDGE_DIM;
    const float* w = Wedge + l * EDGE_DIM * HID;
    float acc = 0.f;
#pragma unroll
    for (int j = 0; j < EDGE_DIM; ++j) acc += tr[j] * w[j * HID + d];
    TE[idx] = (f16)acc;
}

// ---------------- weight prep
__global__ __launch_bounds__(256) void k_wprep(
    const float* __restrict__ Wq, const float* __restrict__ bq,
    const float* __restrict__ Wk, const float* __restrict__ bk,
    const float* __restrict__ Wv, const float* __restrict__ bv,
    const float* __restrict__ Ws, const float* __restrict__ bs,
    f16* __restrict__ wcatT, float* __restrict__ bcat) {
    int idx = blockIdx.x * 256 + threadIdx.x;
    if (idx >= LAYERS * 256 * HID) return;
    int l = idx >> 14;
    int r = idx & 16383;
    int c = r >> 6, kk = r & 63;
    int m = c >> 6, cc = c & 63;
    const float* W = (m == 0) ? Wq : (m == 1) ? Wk : (m == 2) ? Wv : Ws;
    wcatT[idx] = (f16)W[l * 4096 + kk * 64 + cc];
    if (kk == 0) {
        const float* B = (m == 0) ? bq : (m == 1) ? bk : (m == 2) ? bv : bs;
        bcat[l * 256 + c] = B[l * 64 + cc];
    }
}

// ---------------- CSR build
__global__ __launch_bounds__(256) void k_count(const int* __restrict__ dst, int* __restrict__ cnt) {
    int e = blockIdx.x * 256 + threadIdx.x;
    if (e < N_EDGES) atomicAdd(&cnt[dst[e]], 1);
}

__global__ __launch_bounds__(1024) void k_scan1(
    const int* __restrict__ cnt, int* __restrict__ rowptr, int* __restrict__ bsum) {
    __shared__ int wsum[16];
    int t = threadIdx.x;
    int lane = t & 63, w = t >> 6;
    int i = blockIdx.x * 1024 + t;
    int val = (i < N_NODES) ? cnt[i] : 0;
    int incl = val;
#pragma unroll
    for (int o = 1; o < 64; o <<= 1) {
        int u = __shfl_up(incl, o);
        if (lane >= o) incl += u;
    }
    if (lane == 63) wsum[w] = incl;
    __syncthreads();
    int woff = 0;
    for (int j = 0; j < w; ++j) woff += wsum[j];
    int g = woff + incl;
    if (i < N_NODES) rowptr[i + 1] = g;
    if (t == 1023) bsum[blockIdx.x] = g;
}

__global__ __launch_bounds__(64) void k_scan2(int* __restrict__ bsum, int* __restrict__ boff) {
    int l = threadIdx.x;
    int v = (l < SCAN_NBLK) ? bsum[l] : 0;
    int incl = v;
#pragma unroll
    for (int o = 1; o < 64; o <<= 1) {
        int u = __shfl_up(incl, o);
        if (l >= o) incl += u;
    }
    if (l < SCAN_NBLK) boff[l] = incl - v;
}

__global__ __launch_bounds__(1024) void k_scan3(int* __restrict__ rowptr, const int* __restrict__ boff) {
    int i = blockIdx.x * 1024 + threadIdx.x;
    if (i < N_NODES) rowptr[i + 1] += boff[blockIdx.x];
    if (i == 0) rowptr[0] = 0;
}

__global__ __launch_bounds__(256) void k_fill(
    const int* __restrict__ src, const int* __restrict__ dst,
    const int* __restrict__ label, const int* __restrict__ sign,
    const int* __restrict__ rowptr, int* __restrict__ cursor,
    int2* __restrict__ scomb) {
    int e = blockIdx.x * 256 + threadIdx.x;
    if (e >= N_EDGES) return;
    int d = dst[e];
    int pos = atomicAdd(&cursor[d], 1);
    int idx = rowptr[d] + pos;
    scomb[idx] = make_int2(src[e], label[e] * NSIGN + sign[e]);
}

// ---------------- MFMA projection -> q[n][64], kv[n][128] (k|v), sk[n][64]
__global__ __launch_bounds__(256) void k_proj(
    const f16* __restrict__ x16, const f16* __restrict__ wcatT_l,
    const float* __restrict__ bcat_l,
    f16* __restrict__ q, f16* __restrict__ kv, f16* __restrict__ sk) {
    int t = threadIdx.x;
    int w = t >> 6, l = t & 63;
    int n0 = blockIdx.x * 16;
    int rowA = n0 + (l & 15);
    int kb = l >> 4;
    const f16* xr = x16 + (rowA << 6) + (kb << 3);
    f16x8 a0 = *(const f16x8*)(xr);
    f16x8 a1 = *(const f16x8*)(xr + 32);
    int c0 = w << 6;
    int rbase = n0 + ((l >> 4) << 2);
#pragma unroll
    for (int tt = 0; tt < 4; ++tt) {
        int cl = c0 + tt * 16 + (l & 15);
        const f16* wr = wcatT_l + (cl << 6) + (kb << 3);
        f16x8 b0 = *(const f16x8*)(wr);
        f16x8 b1 = *(const f16x8*)(wr + 32);
        f32x4 z = {0.f, 0.f, 0.f, 0.f};
        z = __builtin_amdgcn_mfma_f32_16x16x32_f16(a0, b0, z, 0, 0, 0);
        z = __builtin_amdgcn_mfma_f32_16x16x32_f16(a1, b1, z, 0, 0, 0);
        float bb = bcat_l[cl];
        int cc = cl & 63;
#pragma unroll
        for (int r = 0; r < 4; ++r) {
            int n = rbase + r;
            f16 val = (f16)(z[r] + bb);
            if (w == 0) q[(n << 6) + cc] = val;
            else if (w == 1) kv[(size_t)n * 128 + cc] = val;
            else if (w == 2) kv[(size_t)n * 128 + 64 + cc] = val;
            else sk[(n << 6) + cc] = val;
        }
    }
}

// ---------------- aggregation: lane = (edge-slot e, head h); 8 edges/block-step
__global__ __launch_bounds__(256) void k_agg(
    const f16* __restrict__ q, const f16* __restrict__ kv,
    const f16* __restrict__ sk, const f16* __restrict__ te,
    const int2* __restrict__ scomb, const int* __restrict__ rowptr,
    const float* __restrict__ ln_g, const float* __restrict__ ln_b,
    f16* __restrict__ xout, int do_ln,
    const float* __restrict__ Wp, const float* __restrict__ bp,
    float* __restrict__ pol) {
    int t = threadIdx.x;
    int wid = t >> 6, lane = t & 63;
    int n = blockIdx.x * 4 + wid;
    if (n >= N_NODES) return;
    int e = lane >> 3;  // edge slot 0..7
    int h = lane & 7;   // head 0..7
    f16x8 qf = *(const f16x8*)(q + (n << 6) + (h << 3));
    int rs = rowptr[n], re = rowptr[n + 1];
    const float scale = 0.35355339059327373f;
    float m = -1e30f, lsum = 0.f;
    float acc0 = 0.f, acc1 = 0.f, acc2 = 0.f, acc3 = 0.f;
    float acc4 = 0.f, acc5 = 0.f, acc6 = 0.f, acc7 = 0.f;
    for (int j0 = rs; j0 < re; j0 += 8) {
        int j = j0 + e;
        bool valid = (j < re);
        int jj = valid ? j : (re - 1);
        int2 ec = scomb[jj];
        const f16* kp = kv + ((size_t)ec.x << 7) + (h << 3);
        f16x8 kf = *(const f16x8*)(kp);
        f16x8 vf = *(const f16x8*)(kp + 64);
        f16x8 tf = *(const f16x8*)(te + (ec.y << 6) + (h << 3));
        f16x8 kt = kf + tf;
        float al = dot8(qf, kt, 0.f) * scale;
        al = valid ? al : -1e30f;
        float bm = al;
        bm = fmaxf(bm, __shfl_xor(bm, 8));
        bm = fmaxf(bm, __shfl_xor(bm, 16));
        bm = fmaxf(bm, __shfl_xor(bm, 32));
        float nm = fmaxf(m, bm);
        float c = __expf(m - nm);
        float w = __expf(al - nm);
        lsum = lsum * c + w;
        f16x8 vt = vf + tf;
        acc0 = acc0 * c + w * (float)vt[0];
        acc1 = acc1 * c + w * (float)vt[1];
        acc2 = acc2 * c + w * (float)vt[2];
        acc3 = acc3 * c + w * (float)vt[3];
        acc4 = acc4 * c + w * (float)vt[4];
        acc5 = acc5 * c + w * (float)vt[5];
        acc6 = acc6 * c + w * (float)vt[6];
        acc7 = acc7 * c + w * (float)vt[7];
        m = nm;
    }
    // reduce across the 8 edge-slot lanes of each head (xor 8,16,32)
#pragma unroll
    for (int o = 8; o < 64; o <<= 1) {
        lsum += __shfl_xor(lsum, o);
        acc0 += __shfl_xor(acc0, o);
        acc1 += __shfl_xor(acc1, o);
        acc2 += __shfl_xor(acc2, o);
        acc3 += __shfl_xor(acc3, o);
        acc4 += __shfl_xor(acc4, o);
        acc5 += __shfl_xor(acc5, o);
        acc6 += __shfl_xor(acc6, o);
        acc7 += __shfl_xor(acc7, o);
    }
    // lane (e,h) owns output dim d = h*8+e -> select acc[e] statically
    float av = acc0;
    av = (e == 1) ? acc1 : av;
    av = (e == 2) ? acc2 : av;
    av = (e == 3) ? acc3 : av;
    av = (e == 4) ? acc4 : av;
    av = (e == 5) ? acc5 : av;
    av = (e == 6) ? acc6 : av;
    av = (e == 7) ? acc7 : av;
    int d = (h << 3) + e;
    float outv = av / (lsum + 1e-16f) + (float)sk[(n << 6) + d];
    if (do_ln) {
        float ssum = outv;
#pragma unroll
        for (int o = 1; o < 64; o <<= 1) ssum += __shfl_xor(ssum, o);
        float mu = ssum * (1.f / 64.f);
        float dv = outv - mu;
        float vs = dv * dv;
#pragma unroll
        for (int o = 1; o < 64; o <<= 1) vs += __shfl_xor(vs, o);
        float var = vs * (1.f / 64.f);
        float yv = ln_g[d] * dv / sqrtf(var + EPS) + ln_b[d];
        outv = fmaxf(yv, 0.f);
        xout[(n << 6) + d] = (f16)outv;
    } else {
        xout[(n << 6) + d] = (f16)outv;
        float p0 = outv * Wp[d * 2 + 0];
        float p1 = outv * Wp[d * 2 + 1];
#pragma unroll
        for (int o = 1; o < 64; o <<= 1) {
            p0 += __shfl_xor(p0, o);
            p1 += __shfl_xor(p1, o);
        }
        if (lane == 0) {
            pol[n * 2 + 0] = p0 + bp[0];
            pol[n * 2 + 1] = p1 + bp[1];
        }
    }
}

// ---------------- column sums for the graph mean
__global__ __launch_bounds__(256) void k_colsum(const f16* __restrict__ x16, float* __restrict__ gsum) {
    __shared__ float sh[256];
    int t = threadIdx.x;
    int col = t & 63;
    float acc = 0.f;
    for (int n = blockIdx.x * 4 + (t >> 6); n < N_NODES; n += gridDim.x * 4)
        acc += (float)x16[(n << 6) + col];
    sh[t] = acc;
    __syncthreads();
    if (t < 64) {
        float s = sh[t] + sh[t + 64] + sh[t + 128] + sh[t + 192];
        atomicAdd(&gsum[t], s);
    }
}

// ---------------- value head
__global__ __launch_bounds__(64) void k_value(
    const float* __restrict__ gsum, const float* __restrict__ Wv1,
    const float* __restrict__ bv1, const float* __restrict__ Wv2,
    const float* __restrict__ bv2, float* __restrict__ out) {
    int lane = threadIdx.x;
    float h = bv1[lane];
    for (int i = 0; i < HID; ++i) h += (gsum[i] * (1.f / N_NODES)) * Wv1[i * HID + lane];
    h = fmaxf(h, 0.f);
    float p = h * Wv2[lane];
#pragma unroll
    for (int o = 1; o < 64; o <<= 1) p += __shfl_xor(p, o);
    if (lane == 0) out[0] = tanhf(p + bv2[0]);
}

extern "C" void kernel_launch(void* const* d_in, const int* in_sizes, int n_in,
                              void* d_out, int out_size, void* d_ws, size_t ws_size,
                              hipStream_t stream) {
    const int* x_nodes = (const int*)d_in[0];
    const int* edge_index = (const int*)d_in[1];
    const int* edge_label = (const int*)d_in[2];
    const int* edge_sign = (const int*)d_in[3];
    const float* emb_strand = (const float*)d_in[4];
    const float* emb_pos = (const float*)d_in[5];
    const float* emb_sign = (const float*)d_in[6];
    const float* We = (const float*)d_in[7];
    const float* be = (const float*)d_in[8];
    const float* Wq = (const float*)d_in[9];
    const float* bq = (const float*)d_in[10];
    const float* Wk = (const float*)d_in[11];
    const float* bk = (const float*)d_in[12];
    const float* Wv = (const float*)d_in[13];
    const float* bv = (const float*)d_in[14];
    const float* Wedge = (const float*)d_in[15];
    const float* Wskip = (const float*)d_in[16];
    const float* bskip = (const float*)d_in[17];
    const float* ln_g = (const float*)d_in[18];
    const float* ln_b = (const float*)d_in[19];
    const float* Wp = (const float*)d_in[20];
    const float* bp = (const float*)d_in[21];
    const float* Wv1 = (const float*)d_in[22];
    const float* bv1 = (const float*)d_in[23];
    const float* Wv2 = (const float*)d_in[24];
    const float* bv2 = (const float*)d_in[25];
    float* out = (float*)d_out;

    const int* src = edge_index;
    const int* dst = edge_index + N_EDGES;

    char* ws = (char*)d_ws;
    size_t off = 0;
    auto alloc = [&](size_t bytes) -> void* {
        void* p = ws + off;
        off += (bytes + 255) & ~(size_t)255;
        return p;
    };
    f16* x16 = (f16*)alloc((size_t)N_NODES * HID * 2);
    f16* q = (f16*)alloc((size_t)N_NODES * HID * 2);
    f16* kv = (f16*)alloc((size_t)N_NODES * 128 * 2);
    f16* sk = (f16*)alloc((size_t)N_NODES * HID * 2);
    int2* scomb = (int2*)alloc((size_t)N_EDGES * 8);
    int* rowptr = (int*)alloc((size_t)(N_NODES + 1) * 4);
    int* cnt = (int*)alloc((size_t)N_NODES * 4);
    int* cursor = (int*)alloc((size_t)N_NODES * 4);
    int* bsum = (int*)alloc((size_t)SCAN_NBLK * 4);
    int* boff = (int*)alloc((size_t)SCAN_NBLK * 4);
    float* T = (float*)alloc((size_t)NCOMB * EDGE_DIM * 4);
    f16* TE = (f16*)alloc((size_t)LAYERS * NCOMB * HID * 2);
    f16* wcatT = (f16*)alloc((size_t)LAYERS * 256 * HID * 2);
    float* bcat = (float*)alloc((size_t)LAYERS * 256 * 4);
    float* gsum = (float*)alloc(64 * 4);

    hipMemsetAsync(cnt, 0, (size_t)N_NODES * 4, stream);
    hipMemsetAsync(cursor, 0, (size_t)N_NODES * 4, stream);
    hipMemsetAsync(gsum, 0, 64 * 4, stream);

    k_node_feat<<<(N_NODES * HID + 255) / 256, 256, 0, stream>>>(x_nodes, emb_strand, emb_pos, x16);
    k_tab1<<<(NCOMB * EDGE_DIM + 255) / 256, 256, 0, stream>>>(emb_strand, emb_sign, We, be, T);
    k_tab2<<<(LAYERS * NCOMB * HID + 255) / 256, 256, 0, stream>>>(T, Wedge, TE);
    k_wprep<<<(LAYERS * 256 * HID + 255) / 256, 256, 0, stream>>>(
        Wq, bq, Wk, bk, Wv, bv, Wskip, bskip, wcatT, bcat);
    k_count<<<(N_EDGES + 255) / 256, 256, 0, stream>>>(dst, cnt);
    k_scan1<<<SCAN_NBLK, 1024, 0, stream>>>(cnt, rowptr, bsum);
    k_scan2<<<1, 64, 0, stream>>>(bsum, boff);
    k_scan3<<<SCAN_NBLK, 1024, 0, stream>>>(rowptr, boff);
    k_fill<<<(N_EDGES + 255) / 256, 256, 0, stream>>>(src, dst, edge_label, edge_sign,
                                                      rowptr, cursor, scomb);

    for (int l = 0; l < LAYERS; ++l) {
        k_proj<<<N_NODES / 16, 256, 0, stream>>>(
            x16, wcatT + (size_t)l * 256 * HID, bcat + (size_t)l * 256, q, kv, sk);
        int do_ln = (l < LAYERS - 1) ? 1 : 0;
        const float* lg = do_ln ? (ln_g + (size_t)l * HID) : ln_g;
        const float* lb = do_ln ? (ln_b + (size_t)l * HID) : ln_b;
        k_agg<<<(N_NODES + 3) / 4, 256, 0, stream>>>(
            q, kv, sk, TE + (size_t)l * NCOMB * HID, scomb, rowptr,
            lg, lb, x16, do_ln, Wp, bp, out);
    }

    k_colsum<<<128, 256, 0, stream>>>(x16, gsum);
    k_value<<<1, 64, 0, stream>>>(gsum, Wv1, bv1, Wv2, bv2, out + 2 * N_NODES);
}

// Round 5
// 482.803 us; speedup vs baseline: 3.0526x; 1.0628x over previous
//
#include <hip/hip_runtime.h>
#include <math.h>

typedef _Float16 f16;
typedef _Float16 f16x8 __attribute__((ext_vector_type(8)));
typedef float f32x4 __attribute__((ext_vector_type(4)));

#define N_NODES 50000
#define N_EDGES 800000
#define HID 64
#define HEADS 8
#define DH 8
#define LAYERS 6
#define EDGE_DIM 16
#define SIGN_DIM 8
#define NSIGN 3
#define VOC 512
#define NCOMB (VOC * NSIGN)
#define EPS 1e-5f
#define SCAN_NBLK ((N_NODES + 1023) / 1024)

// coarse-bucket sort params
#define NBUCK 196     // ceil(50000/256) buckets of 256 dst nodes
#define BUCK_CAP 5120 // avg 4096 edges/bucket, 16-sigma margin
#define BIN_EPB 4096  // edges per phase-1 block
#define BIN_EPT 16    // edges per thread
#define BIN_NBLK ((N_EDGES + BIN_EPB - 1) / BIN_EPB)

__device__ __forceinline__ float dot8(f16x8 a, f16x8 b, float c) {
#if __has_builtin(__builtin_amdgcn_fdot2)
    c = __builtin_amdgcn_fdot2(__builtin_shufflevector(a, a, 0, 1),
                               __builtin_shufflevector(b, b, 0, 1), c, false);
    c = __builtin_amdgcn_fdot2(__builtin_shufflevector(a, a, 2, 3),
                               __builtin_shufflevector(b, b, 2, 3), c, false);
    c = __builtin_amdgcn_fdot2(__builtin_shufflevector(a, a, 4, 5),
                               __builtin_shufflevector(b, b, 4, 5), c, false);
    c = __builtin_amdgcn_fdot2(__builtin_shufflevector(a, a, 6, 7),
                               __builtin_shufflevector(b, b, 6, 7), c, false);
#else
#pragma unroll
    for (int i = 0; i < 8; ++i) c += (float)a[i] * (float)b[i];
#endif
    return c;
}

// ---------------- node features -> fp16
__global__ __launch_bounds__(256) void k_node_feat(
    const int* __restrict__ xn, const float* __restrict__ emb_s,
    const float* __restrict__ emb_p, f16* __restrict__ x16) {
    int idx = blockIdx.x * 256 + threadIdx.x;
    if (idx >= N_NODES * HID) return;
    int n = idx >> 6, d = idx & 63;
    float acc = 0.f;
#pragma unroll
    for (int s = 0; s < 4; ++s) {
        int id = xn[n * 4 + s];
        acc += emb_s[id * HID + d] + emb_p[s * HID + d];
    }
    x16[idx] = (f16)acc;
}

// ---------------- ef table
__global__ __launch_bounds__(256) void k_tab1(
    const float* __restrict__ emb_s, const float* __restrict__ emb_sg,
    const float* __restrict__ We, const float* __restrict__ be,
    float* __restrict__ T) {
    int gid = blockIdx.x * 256 + threadIdx.x;
    int comb = gid >> 4, c = gid & 15;
    if (comb >= NCOMB) return;
    int lb = comb / NSIGN, sg = comb % NSIGN;
    float acc = be[c];
    const float* er = emb_s + lb * HID;
#pragma unroll
    for (int j = 0; j < HID; ++j) acc += er[j] * We[j * EDGE_DIM + c];
    const float* sr = emb_sg + sg * SIGN_DIM;
#pragma unroll
    for (int j = 0; j < SIGN_DIM; ++j) acc += sr[j] * We[(HID + j) * EDGE_DIM + c];
    T[comb * EDGE_DIM + c] = acc;
}

// ---------------- per-layer edge-contribution table (fp16)
__global__ __launch_bounds__(256) void k_tab2(
    const float* __restrict__ T, const float* __restrict__ Wedge,
    f16* __restrict__ TE) {
    int idx = blockIdx.x * 256 + threadIdx.x;
    if (idx >= LAYERS * NCOMB * HID) return;
    int l = idx / (NCOMB * HID);
    int r = idx - l * (NCOMB * HID);
    int comb = r >> 6, d = r & 63;
    const float* tr = T + comb * EDGE_DIM;
    const float* w = Wedge + l * EDGE_DIM * HID;
    float acc = 0.f;
#pragma unroll
    for (int j = 0; j < EDGE_DIM; ++j) acc += tr[j] * w[j * HID + d];
    TE[idx] = (f16)acc;
}

// ---------------- weight prep
__global__ __launch_bounds__(256) void k_wprep(
    const float* __restrict__ Wq, const float* __restrict__ bq,
    const float* __restrict__ Wk, const float* __restrict__ bk,
    const float* __restrict__ Wv, const float* __restrict__ bv,
    const float* __restrict__ Ws, const float* __restrict__ bs,
    f16* __restrict__ wcatT, float* __restrict__ bcat) {
    int idx = blockIdx.x * 256 + threadIdx.x;
    if (idx >= LAYERS * 256 * HID) return;
    int l = idx >> 14;
    int r = idx & 16383;
    int c = r >> 6, kk = r & 63;
    int m = c >> 6, cc = c & 63;
    const float* W = (m == 0) ? Wq : (m == 1) ? Wk : (m == 2) ? Wv : Ws;
    wcatT[idx] = (f16)W[l * 4096 + kk * 64 + cc];
    if (kk == 0) {
        const float* B = (m == 0) ? bq : (m == 1) ? bk : (m == 2) ? bv : bs;
        bcat[l * 256 + c] = B[l * 64 + cc];
    }
}

// ---------------- CSR build: count + two-level scan
__global__ __launch_bounds__(256) void k_count(const int* __restrict__ dst, int* __restrict__ cnt) {
    int e = blockIdx.x * 256 + threadIdx.x;
    if (e < N_EDGES) atomicAdd(&cnt[dst[e]], 1);
}

__global__ __launch_bounds__(1024) void k_scan1(
    const int* __restrict__ cnt, int* __restrict__ rowptr, int* __restrict__ bsum) {
    __shared__ int wsum[16];
    int t = threadIdx.x;
    int lane = t & 63, w = t >> 6;
    int i = blockIdx.x * 1024 + t;
    int val = (i < N_NODES) ? cnt[i] : 0;
    int incl = val;
#pragma unroll
    for (int o = 1; o < 64; o <<= 1) {
        int u = __shfl_up(incl, o);
        if (lane >= o) incl += u;
    }
    if (lane == 63) wsum[w] = incl;
    __syncthreads();
    int woff = 0;
    for (int j = 0; j < w; ++j) woff += wsum[j];
    int g = woff + incl;
    if (i < N_NODES) rowptr[i + 1] = g;
    if (t == 1023) bsum[blockIdx.x] = g;
}

__global__ __launch_bounds__(64) void k_scan2(int* __restrict__ bsum, int* __restrict__ boff) {
    int l = threadIdx.x;
    int v = (l < SCAN_NBLK) ? bsum[l] : 0;
    int incl = v;
#pragma unroll
    for (int o = 1; o < 64; o <<= 1) {
        int u = __shfl_up(incl, o);
        if (l >= o) incl += u;
    }
    if (l < SCAN_NBLK) boff[l] = incl - v;
}

__global__ __launch_bounds__(1024) void k_scan3(int* __restrict__ rowptr, const int* __restrict__ boff) {
    int i = blockIdx.x * 1024 + threadIdx.x;
    if (i < N_NODES) rowptr[i + 1] += boff[blockIdx.x];
    if (i == 0) rowptr[0] = 0;
}

// ---------------- phase 1: bin edges into coarse buckets (write-coalesced segments)
__global__ __launch_bounds__(256) void k_bin(
    const int* __restrict__ src, const int* __restrict__ dst,
    const int* __restrict__ label, const int* __restrict__ sign,
    int* __restrict__ bcur, int2* __restrict__ buf) {
    __shared__ int hist[NBUCK];
    __shared__ int base[NBUCK];
    int t = threadIdx.x;
    for (int i = t; i < NBUCK; i += 256) hist[i] = 0;
    __syncthreads();
    int e0 = blockIdx.x * BIN_EPB;
    int pk[BIN_EPT], dl[BIN_EPT], bl[BIN_EPT], loc[BIN_EPT];
#pragma unroll
    for (int i = 0; i < BIN_EPT; ++i) {
        int e = e0 + i * 256 + t;
        bool vld = e < N_EDGES;
        int d = vld ? dst[e] : 0;
        bl[i] = d >> 8;
        dl[i] = d & 255;
        pk[i] = vld ? ((src[e] << 11) | (label[e] * NSIGN + sign[e])) : 0;
        loc[i] = vld ? atomicAdd(&hist[bl[i]], 1) : -1;
    }
    __syncthreads();
    if (t < NBUCK) {
        int h = hist[t];
        int gb = h ? atomicAdd(&bcur[t], h) : 0;
        base[t] = t * BUCK_CAP + gb;
    }
    __syncthreads();
#pragma unroll
    for (int i = 0; i < BIN_EPT; ++i)
        if (loc[i] >= 0) buf[base[bl[i]] + loc[i]] = make_int2(pk[i], dl[i]);
}

// ---------------- phase 2: place bucket records into final CSR order
__global__ __launch_bounds__(256) void k_place(
    const int* __restrict__ bcur, const int2* __restrict__ buf,
    const int* __restrict__ rowptr, int* __restrict__ scomb) {
    __shared__ int lcur[256];
    int t = threadIdx.x;
    int b = blockIdx.x;
    lcur[t] = 0;
    __syncthreads();
    int cnt = bcur[b];
    for (int i = t; i < cnt; i += 256) {
        int2 r = buf[b * BUCK_CAP + i];
        int pos = atomicAdd(&lcur[r.y], 1);
        int d = (b << 8) + r.y;
        scomb[rowptr[d] + pos] = r.x;
    }
}

// ---------------- MFMA projection -> q[n][64], kv[n][128] (k|v), sk[n][64]
__global__ __launch_bounds__(256) void k_proj(
    const f16* __restrict__ x16, const f16* __restrict__ wcatT_l,
    const float* __restrict__ bcat_l,
    f16* __restrict__ q, f16* __restrict__ kv, f16* __restrict__ sk) {
    int t = threadIdx.x;
    int w = t >> 6, l = t & 63;
    int n0 = blockIdx.x * 16;
    int rowA = n0 + (l & 15);
    int kb = l >> 4;
    const f16* xr = x16 + (rowA << 6) + (kb << 3);
    f16x8 a0 = *(const f16x8*)(xr);
    f16x8 a1 = *(const f16x8*)(xr + 32);
    int c0 = w << 6;
    int rbase = n0 + ((l >> 4) << 2);
#pragma unroll
    for (int tt = 0; tt < 4; ++tt) {
        int cl = c0 + tt * 16 + (l & 15);
        const f16* wr = wcatT_l + (cl << 6) + (kb << 3);
        f16x8 b0 = *(const f16x8*)(wr);
        f16x8 b1 = *(const f16x8*)(wr + 32);
        f32x4 z = {0.f, 0.f, 0.f, 0.f};
        z = __builtin_amdgcn_mfma_f32_16x16x32_f16(a0, b0, z, 0, 0, 0);
        z = __builtin_amdgcn_mfma_f32_16x16x32_f16(a1, b1, z, 0, 0, 0);
        float bb = bcat_l[cl];
        int cc = cl & 63;
#pragma unroll
        for (int r = 0; r < 4; ++r) {
            int n = rbase + r;
            f16 val = (f16)(z[r] + bb);
            if (w == 0) q[(n << 6) + cc] = val;
            else if (w == 1) kv[(size_t)n * 128 + cc] = val;
            else if (w == 2) kv[(size_t)n * 128 + 64 + cc] = val;
            else sk[(n << 6) + cc] = val;
        }
    }
}

// ---------------- aggregation: lane = (edge-slot e, head h); 16 edges per iteration
__global__ __launch_bounds__(256) void k_agg(
    const f16* __restrict__ q, const f16* __restrict__ kv,
    const f16* __restrict__ sk, const f16* __restrict__ te,
    const int* __restrict__ scomb, const int* __restrict__ rowptr,
    const float* __restrict__ ln_g, const float* __restrict__ ln_b,
    f16* __restrict__ xout, int do_ln,
    const float* __restrict__ Wp, const float* __restrict__ bp,
    float* __restrict__ pol) {
    int t = threadIdx.x;
    int wid = t >> 6, lane = t & 63;
    int n = blockIdx.x * 4 + wid;
    if (n >= N_NODES) return;
    int e = lane >> 3;  // edge slot 0..7
    int h = lane & 7;   // head 0..7
    f16x8 qf = *(const f16x8*)(q + (n << 6) + (h << 3));
    int rs = rowptr[n], re = rowptr[n + 1];
    const float scale = 0.35355339059327373f;
    float m = -1e30f, lsum = 0.f;
    float acc0 = 0.f, acc1 = 0.f, acc2 = 0.f, acc3 = 0.f;
    float acc4 = 0.f, acc5 = 0.f, acc6 = 0.f, acc7 = 0.f;
    for (int j0 = rs; j0 < re; j0 += 16) {
        int ja = j0 + e, jb = j0 + 8 + e;
        bool va = ja < re, vb = jb < re;
        int pa = scomb[va ? ja : re - 1];
        int pb = scomb[vb ? jb : re - 1];
        const f16* kpa = kv + ((size_t)(pa >> 11) << 7) + (h << 3);
        const f16* kpb = kv + ((size_t)(pb >> 11) << 7) + (h << 3);
        f16x8 ka = *(const f16x8*)(kpa);
        f16x8 vaf = *(const f16x8*)(kpa + 64);
        f16x8 ta = *(const f16x8*)(te + ((pa & 2047) << 6) + (h << 3));
        f16x8 kb = *(const f16x8*)(kpb);
        f16x8 vbf = *(const f16x8*)(kpb + 64);
        f16x8 tb = *(const f16x8*)(te + ((pb & 2047) << 6) + (h << 3));
        float ala = dot8(qf, ka + ta, 0.f) * scale;
        float alb = dot8(qf, kb + tb, 0.f) * scale;
        ala = va ? ala : -1e30f;
        alb = vb ? alb : -1e30f;
        float bm = fmaxf(ala, alb);
        bm = fmaxf(bm, __shfl_xor(bm, 8));
        bm = fmaxf(bm, __shfl_xor(bm, 16));
        bm = fmaxf(bm, __shfl_xor(bm, 32));
        float nm = fmaxf(m, bm);
        float c = __expf(m - nm);
        float wa = __expf(ala - nm);
        float wb = __expf(alb - nm);
        lsum = lsum * c + wa + wb;
        f16x8 vta = vaf + ta;
        f16x8 vtb = vbf + tb;
        acc0 = acc0 * c + wa * (float)vta[0] + wb * (float)vtb[0];
        acc1 = acc1 * c + wa * (float)vta[1] + wb * (float)vtb[1];
        acc2 = acc2 * c + wa * (float)vta[2] + wb * (float)vtb[2];
        acc3 = acc3 * c + wa * (float)vta[3] + wb * (float)vtb[3];
        acc4 = acc4 * c + wa * (float)vta[4] + wb * (float)vtb[4];
        acc5 = acc5 * c + wa * (float)vta[5] + wb * (float)vtb[5];
        acc6 = acc6 * c + wa * (float)vta[6] + wb * (float)vtb[6];
        acc7 = acc7 * c + wa * (float)vta[7] + wb * (float)vtb[7];
        m = nm;
    }
    // reduce across the 8 edge-slot lanes of each head
#pragma unroll
    for (int o = 8; o < 64; o <<= 1) {
        lsum += __shfl_xor(lsum, o);
        acc0 += __shfl_xor(acc0, o);
        acc1 += __shfl_xor(acc1, o);
        acc2 += __shfl_xor(acc2, o);
        acc3 += __shfl_xor(acc3, o);
        acc4 += __shfl_xor(acc4, o);
        acc5 += __shfl_xor(acc5, o);
        acc6 += __shfl_xor(acc6, o);
        acc7 += __shfl_xor(acc7, o);
    }
    float av = acc0;
    av = (e == 1) ? acc1 : av;
    av = (e == 2) ? acc2 : av;
    av = (e == 3) ? acc3 : av;
    av = (e == 4) ? acc4 : av;
    av = (e == 5) ? acc5 : av;
    av = (e == 6) ? acc6 : av;
    av = (e == 7) ? acc7 : av;
    int d = (h << 3) + e;
    float outv = av / (lsum + 1e-16f) + (float)sk[(n << 6) + d];
    if (do_ln) {
        float ssum = outv;
#pragma unroll
        for (int o = 1; o < 64; o <<= 1) ssum += __shfl_xor(ssum, o);
        float mu = ssum * (1.f / 64.f);
        float dv = outv - mu;
        float vs = dv * dv;
#pragma unroll
        for (int o = 1; o < 64; o <<= 1) vs += __shfl_xor(vs, o);
        float var = vs * (1.f / 64.f);
        float yv = ln_g[d] * dv / sqrtf(var + EPS) + ln_b[d];
        outv = fmaxf(yv, 0.f);
        xout[(n << 6) + d] = (f16)outv;
    } else {
        xout[(n << 6) + d] = (f16)outv;
        float p0 = outv * Wp[d * 2 + 0];
        float p1 = outv * Wp[d * 2 + 1];
#pragma unroll
        for (int o = 1; o < 64; o <<= 1) {
            p0 += __shfl_xor(p0, o);
            p1 += __shfl_xor(p1, o);
        }
        if (lane == 0) {
            pol[n * 2 + 0] = p0 + bp[0];
            pol[n * 2 + 1] = p1 + bp[1];
        }
    }
}

// ---------------- column sums for the graph mean
__global__ __launch_bounds__(256) void k_colsum(const f16* __restrict__ x16, float* __restrict__ gsum) {
    __shared__ float sh[256];
    int t = threadIdx.x;
    int col = t & 63;
    float acc = 0.f;
    for (int n = blockIdx.x * 4 + (t >> 6); n < N_NODES; n += gridDim.x * 4)
        acc += (float)x16[(n << 6) + col];
    sh[t] = acc;
    __syncthreads();
    if (t < 64) {
        float s = sh[t] + sh[t + 64] + sh[t + 128] + sh[t + 192];
        atomicAdd(&gsum[t], s);
    }
}

// ---------------- value head
__global__ __launch_bounds__(64) void k_value(
    const float* __restrict__ gsum, const float* __restrict__ Wv1,
    const float* __restrict__ bv1, const float* __restrict__ Wv2,
    const float* __restrict__ bv2, float* __restrict__ out) {
    int lane = threadIdx.x;
    float h = bv1[lane];
    for (int i = 0; i < HID; ++i) h += (gsum[i] * (1.f / N_NODES)) * Wv1[i * HID + lane];
    h = fmaxf(h, 0.f);
    float p = h * Wv2[lane];
#pragma unroll
    for (int o = 1; o < 64; o <<= 1) p += __shfl_xor(p, o);
    if (lane == 0) out[0] = tanhf(p + bv2[0]);
}

extern "C" void kernel_launch(void* const* d_in, const int* in_sizes, int n_in,
                              void* d_out, int out_size, void* d_ws, size_t ws_size,
                              hipStream_t stream) {
    const int* x_nodes = (const int*)d_in[0];
    const int* edge_index = (const int*)d_in[1];
    const int* edge_label = (const int*)d_in[2];
    const int* edge_sign = (const int*)d_in[3];
    const float* emb_strand = (const float*)d_in[4];
    const float* emb_pos = (const float*)d_in[5];
    const float* emb_sign = (const float*)d_in[6];
    const float* We = (const float*)d_in[7];
    const float* be = (const float*)d_in[8];
    const float* Wq = (const float*)d_in[9];
    const float* bq = (const float*)d_in[10];
    const float* Wk = (const float*)d_in[11];
    const float* bk = (const float*)d_in[12];
    const float* Wv = (const float*)d_in[13];
    const float* bv = (const float*)d_in[14];
    const float* Wedge = (const float*)d_in[15];
    const float* Wskip = (const float*)d_in[16];
    const float* bskip = (const float*)d_in[17];
    const float* ln_g = (const float*)d_in[18];
    const float* ln_b = (const float*)d_in[19];
    const float* Wp = (const float*)d_in[20];
    const float* bp = (const float*)d_in[21];
    const float* Wv1 = (const float*)d_in[22];
    const float* bv1 = (const float*)d_in[23];
    const float* Wv2 = (const float*)d_in[24];
    const float* bv2 = (const float*)d_in[25];
    float* out = (float*)d_out;

    const int* src = edge_index;
    const int* dst = edge_index + N_EDGES;

    char* ws = (char*)d_ws;
    size_t off = 0;
    auto alloc = [&](size_t bytes) -> void* {
        void* p = ws + off;
        off += (bytes + 255) & ~(size_t)255;
        return p;
    };
    f16* x16 = (f16*)alloc((size_t)N_NODES * HID * 2);
    f16* q = (f16*)alloc((size_t)N_NODES * HID * 2);
    f16* kv = (f16*)alloc((size_t)N_NODES * 128 * 2);
    f16* sk = (f16*)alloc((size_t)N_NODES * HID * 2);
    int* scomb = (int*)alloc((size_t)N_EDGES * 4);
    int2* binbuf = (int2*)alloc((size_t)NBUCK * BUCK_CAP * 8);
    int* rowptr = (int*)alloc((size_t)(N_NODES + 1) * 4);
    int* cnt = (int*)alloc((size_t)N_NODES * 4);
    int* bcur = (int*)alloc((size_t)NBUCK * 4);
    int* bsum = (int*)alloc((size_t)SCAN_NBLK * 4);
    int* boff = (int*)alloc((size_t)SCAN_NBLK * 4);
    float* T = (float*)alloc((size_t)NCOMB * EDGE_DIM * 4);
    f16* TE = (f16*)alloc((size_t)LAYERS * NCOMB * HID * 2);
    f16* wcatT = (f16*)alloc((size_t)LAYERS * 256 * HID * 2);
    float* bcat = (float*)alloc((size_t)LAYERS * 256 * 4);
    float* gsum = (float*)alloc(64 * 4);

    hipMemsetAsync(cnt, 0, (size_t)N_NODES * 4, stream);
    hipMemsetAsync(bcur, 0, (size_t)NBUCK * 4, stream);
    hipMemsetAsync(gsum, 0, 64 * 4, stream);

    k_node_feat<<<(N_NODES * HID + 255) / 256, 256, 0, stream>>>(x_nodes, emb_strand, emb_pos, x16);
    k_tab1<<<(NCOMB * EDGE_DIM + 255) / 256, 256, 0, stream>>>(emb_strand, emb_sign, We, be, T);
    k_tab2<<<(LAYERS * NCOMB * HID + 255) / 256, 256, 0, stream>>>(T, Wedge, TE);
    k_wprep<<<(LAYERS * 256 * HID + 255) / 256, 256, 0, stream>>>(
        Wq, bq, Wk, bk, Wv, bv, Wskip, bskip, wcatT, bcat);
    k_count<<<(N_EDGES + 255) / 256, 256, 0, stream>>>(dst, cnt);
    k_scan1<<<SCAN_NBLK, 1024, 0, stream>>>(cnt, rowptr, bsum);
    k_scan2<<<1, 64, 0, stream>>>(bsum, boff);
    k_scan3<<<SCAN_NBLK, 1024, 0, stream>>>(rowptr, boff);
    k_bin<<<BIN_NBLK, 256, 0, stream>>>(src, dst, edge_label, edge_sign, bcur, binbuf);
    k_place<<<NBUCK, 256, 0, stream>>>(bcur, binbuf, rowptr, scomb);

    for (int l = 0; l < LAYERS; ++l) {
        k_proj<<<N_NODES / 16, 256, 0, stream>>>(
            x16, wcatT + (size_t)l * 256 * HID, bcat + (size_t)l * 256, q, kv, sk);
        int do_ln = (l < LAYERS - 1) ? 1 : 0;
        const float* lg = do_ln ? (ln_g + (size_t)l * HID) : ln_g;
        const float* lb = do_ln ? (ln_b + (size_t)l * HID) : ln_b;
        k_agg<<<(N_NODES + 3) / 4, 256, 0, stream>>>(
            q, kv, sk, TE + (size_t)l * NCOMB * HID, scomb, rowptr,
            lg, lb, x16, do_ln, Wp, bp, out);
    }

    k_colsum<<<128, 256, 0, stream>>>(x16, gsum);
    k_value<<<1, 64, 0, stream>>>(gsum, Wv1, bv1, Wv2, bv2, out + 2 * N_NODES);
}

// Round 6
// 423.656 us; speedup vs baseline: 3.4788x; 1.1396x over previous
//
#include <hip/hip_runtime.h>
#include <math.h>

typedef _Float16 f16;
typedef _Float16 f16x8 __attribute__((ext_vector_type(8)));
typedef float f32x4 __attribute__((ext_vector_type(4)));

#define N_NODES 50000
#define N_EDGES 800000
#define HID 64
#define HEADS 8
#define DH 8
#define LAYERS 6
#define EDGE_DIM 16
#define SIGN_DIM 8
#define NSIGN 3
#define VOC 512
#define NCOMB (VOC * NSIGN)
#define EPS 1e-5f

// coarse-bucket sort params
#define NBUCK 196     // ceil(50000/256) buckets of 256 dst nodes
#define BUCK_CAP 5120 // avg 4096 edges/bucket, 16-sigma margin
#define BIN_EPB 4096  // edges per phase-1 block
#define BIN_EPT 16    // edges per thread
#define BIN_NBLK ((N_EDGES + BIN_EPB - 1) / BIN_EPB)

__device__ __forceinline__ float dot8(f16x8 a, f16x8 b, float c) {
#if __has_builtin(__builtin_amdgcn_fdot2)
    c = __builtin_amdgcn_fdot2(__builtin_shufflevector(a, a, 0, 1),
                               __builtin_shufflevector(b, b, 0, 1), c, false);
    c = __builtin_amdgcn_fdot2(__builtin_shufflevector(a, a, 2, 3),
                               __builtin_shufflevector(b, b, 2, 3), c, false);
    c = __builtin_amdgcn_fdot2(__builtin_shufflevector(a, a, 4, 5),
                               __builtin_shufflevector(b, b, 4, 5), c, false);
    c = __builtin_amdgcn_fdot2(__builtin_shufflevector(a, a, 6, 7),
                               __builtin_shufflevector(b, b, 6, 7), c, false);
#else
#pragma unroll
    for (int i = 0; i < 8; ++i) c += (float)a[i] * (float)b[i];
#endif
    return c;
}

// ---------------- node features -> fp16
__global__ __launch_bounds__(256) void k_node_feat(
    const int* __restrict__ xn, const float* __restrict__ emb_s,
    const float* __restrict__ emb_p, f16* __restrict__ x16) {
    int idx = blockIdx.x * 256 + threadIdx.x;
    if (idx >= N_NODES * HID) return;
    int n = idx >> 6, d = idx & 63;
    float acc = 0.f;
#pragma unroll
    for (int s = 0; s < 4; ++s) {
        int id = xn[n * 4 + s];
        acc += emb_s[id * HID + d] + emb_p[s * HID + d];
    }
    x16[idx] = (f16)acc;
}

// ---------------- merged edge tables: T (LDS) -> TE[l][comb][d] (fp16)
__global__ __launch_bounds__(256) void k_tabTE(
    const float* __restrict__ emb_s, const float* __restrict__ emb_sg,
    const float* __restrict__ We, const float* __restrict__ be,
    const float* __restrict__ Wedge, f16* __restrict__ TE) {
    __shared__ float T[16][16];
    int t = threadIdx.x;
    int comb0 = blockIdx.x * 16;
    int cl = t >> 4, c = t & 15;
    int comb = comb0 + cl;
    int lb = comb / NSIGN, sg = comb % NSIGN;
    float acc = be[c];
    const float* er = emb_s + lb * HID;
#pragma unroll
    for (int j = 0; j < HID; ++j) acc += er[j] * We[j * EDGE_DIM + c];
    const float* sr = emb_sg + sg * SIGN_DIM;
#pragma unroll
    for (int j = 0; j < SIGN_DIM; ++j) acc += sr[j] * We[(HID + j) * EDGE_DIM + c];
    T[cl][c] = acc;
    __syncthreads();
    for (int l = 0; l < LAYERS; ++l) {
        const float* w = Wedge + l * EDGE_DIM * HID;
#pragma unroll
        for (int rep = 0; rep < 4; ++rep) {
            int idx = rep * 256 + t;
            int cml = idx >> 6, d = idx & 63;
            float a = 0.f;
#pragma unroll
            for (int j = 0; j < EDGE_DIM; ++j) a += T[cml][j] * w[j * HID + d];
            TE[((size_t)l * NCOMB + comb0 + cml) * HID + d] = (f16)a;
        }
    }
}

// ---------------- weight prep
__global__ __launch_bounds__(256) void k_wprep(
    const float* __restrict__ Wq, const float* __restrict__ bq,
    const float* __restrict__ Wk, const float* __restrict__ bk,
    const float* __restrict__ Wv, const float* __restrict__ bv,
    const float* __restrict__ Ws, const float* __restrict__ bs,
    f16* __restrict__ wcatT, float* __restrict__ bcat) {
    int idx = blockIdx.x * 256 + threadIdx.x;
    if (idx >= LAYERS * 256 * HID) return;
    int l = idx >> 14;
    int r = idx & 16383;
    int c = r >> 6, kk = r & 63;
    int m = c >> 6, cc = c & 63;
    const float* W = (m == 0) ? Wq : (m == 1) ? Wk : (m == 2) ? Wv : Ws;
    wcatT[idx] = (f16)W[l * 4096 + kk * 64 + cc];
    if (kk == 0) {
        const float* B = (m == 0) ? bq : (m == 1) ? bk : (m == 2) ? bv : bs;
        bcat[l * 256 + c] = B[l * 64 + cc];
    }
}

// ---------------- phase 1: bin edges into coarse buckets
__global__ __launch_bounds__(256) void k_bin(
    const int* __restrict__ src, const int* __restrict__ dst,
    const int* __restrict__ label, const int* __restrict__ sign,
    int* __restrict__ bcur, int2* __restrict__ buf) {
    __shared__ int hist[NBUCK];
    __shared__ int base[NBUCK];
    int t = threadIdx.x;
    for (int i = t; i < NBUCK; i += 256) hist[i] = 0;
    __syncthreads();
    int e0 = blockIdx.x * BIN_EPB;
    int pk[BIN_EPT], dl[BIN_EPT], bl[BIN_EPT], loc[BIN_EPT];
#pragma unroll
    for (int i = 0; i < BIN_EPT; ++i) {
        int e = e0 + i * 256 + t;
        bool vld = e < N_EDGES;
        int d = vld ? dst[e] : 0;
        bl[i] = d >> 8;
        dl[i] = d & 255;
        pk[i] = vld ? ((src[e] << 11) | (label[e] * NSIGN + sign[e])) : 0;
        loc[i] = vld ? atomicAdd(&hist[bl[i]], 1) : -1;
    }
    __syncthreads();
    if (t < NBUCK) {
        int h = hist[t];
        int gb = h ? atomicAdd(&bcur[t], h) : 0;
        base[t] = t * BUCK_CAP + gb;
    }
    __syncthreads();
#pragma unroll
    for (int i = 0; i < BIN_EPT; ++i)
        if (loc[i] >= 0) buf[base[bl[i]] + loc[i]] = make_int2(pk[i], dl[i]);
}

// ---------------- bucket-total exclusive scan (+ misc inits)
__global__ __launch_bounds__(256) void k_bscan(
    const int* __restrict__ bcur, int* __restrict__ bbase,
    int* __restrict__ rowptr, float* __restrict__ gsum) {
    __shared__ int ws[4];
    int t = threadIdx.x;
    int lane = t & 63, w = t >> 6;
    int v = (t < NBUCK) ? bcur[t] : 0;
    int incl = v;
#pragma unroll
    for (int o = 1; o < 64; o <<= 1) {
        int u = __shfl_up(incl, o);
        if (lane >= o) incl += u;
    }
    if (lane == 63) ws[w] = incl;
    __syncthreads();
    int woff = 0;
    for (int j = 0; j < w; ++j) woff += ws[j];
    if (t < NBUCK) bbase[t] = woff + incl - v;  // exclusive base
    if (t == 0) rowptr[N_NODES] = N_EDGES;
    if (t < 64) gsum[t] = 0.f;
}

// ---------------- phase 2: per-bucket rowptr build + CSR scatter
__global__ __launch_bounds__(256) void k_place(
    const int* __restrict__ bcur, const int* __restrict__ bbase,
    const int2* __restrict__ buf, int* __restrict__ rowptr,
    int* __restrict__ scomb) {
    __shared__ int hist[256];
    __shared__ int curs[256];
    __shared__ int ws[4];
    int t = threadIdx.x, b = blockIdx.x;
    hist[t] = 0;
    __syncthreads();
    int cnt = bcur[b];
    const int2* bb = buf + (size_t)b * BUCK_CAP;
    for (int i = t; i < cnt; i += 256) atomicAdd(&hist[bb[i].y], 1);
    __syncthreads();
    int v = hist[t];
    int lane = t & 63, w = t >> 6;
    int incl = v;
#pragma unroll
    for (int o = 1; o < 64; o <<= 1) {
        int u = __shfl_up(incl, o);
        if (lane >= o) incl += u;
    }
    if (lane == 63) ws[w] = incl;
    __syncthreads();
    int woff = 0;
    for (int j = 0; j < w; ++j) woff += ws[j];
    int start = bbase[b] + woff + incl - v;
    int n = (b << 8) + t;
    if (n < N_NODES) rowptr[n] = start;
    curs[t] = start;
    __syncthreads();
    for (int i = t; i < cnt; i += 256) {
        int2 r = bb[i];
        int pos = atomicAdd(&curs[r.y], 1);
        scomb[pos] = r.x;
    }
}

// ---------------- MFMA projection -> q[n][64], kv[n][128] (k|v), sk[n][64]
__global__ __launch_bounds__(256) void k_proj(
    const f16* __restrict__ x16, const f16* __restrict__ wcatT_l,
    const float* __restrict__ bcat_l,
    f16* __restrict__ q, f16* __restrict__ kv, f16* __restrict__ sk) {
    int t = threadIdx.x;
    int w = t >> 6, l = t & 63;
    int n0 = blockIdx.x * 16;
    int rowA = n0 + (l & 15);
    int kb = l >> 4;
    const f16* xr = x16 + (rowA << 6) + (kb << 3);
    f16x8 a0 = *(const f16x8*)(xr);
    f16x8 a1 = *(const f16x8*)(xr + 32);
    int c0 = w << 6;
    int rbase = n0 + ((l >> 4) << 2);
#pragma unroll
    for (int tt = 0; tt < 4; ++tt) {
        int cl = c0 + tt * 16 + (l & 15);
        const f16* wr = wcatT_l + (cl << 6) + (kb << 3);
        f16x8 b0 = *(const f16x8*)(wr);
        f16x8 b1 = *(const f16x8*)(wr + 32);
        f32x4 z = {0.f, 0.f, 0.f, 0.f};
        z = __builtin_amdgcn_mfma_f32_16x16x32_f16(a0, b0, z, 0, 0, 0);
        z = __builtin_amdgcn_mfma_f32_16x16x32_f16(a1, b1, z, 0, 0, 0);
        float bb = bcat_l[cl];
        int cc = cl & 63;
#pragma unroll
        for (int r = 0; r < 4; ++r) {
            int n = rbase + r;
            f16 val = (f16)(z[r] + bb);
            if (w == 0) q[(n << 6) + cc] = val;
            else if (w == 1) kv[(size_t)n * 128 + cc] = val;
            else if (w == 2) kv[(size_t)n * 128 + 64 + cc] = val;
            else sk[(n << 6) + cc] = val;
        }
    }
}

// ---------------- aggregation (no-max softmax, shift-invariant): 16 edges/iter
__global__ __launch_bounds__(256) void k_agg(
    const f16* __restrict__ q, const f16* __restrict__ kv,
    const f16* __restrict__ sk, const f16* __restrict__ te,
    const int* __restrict__ scomb, const int* __restrict__ rowptr,
    const float* __restrict__ ln_g, const float* __restrict__ ln_b,
    f16* __restrict__ xout, int do_ln,
    const float* __restrict__ Wp, const float* __restrict__ bp,
    float* __restrict__ pol) {
    int t = threadIdx.x;
    int wid = t >> 6, lane = t & 63;
    int n = blockIdx.x * 4 + wid;
    if (n >= N_NODES) return;
    int e = lane >> 3;  // edge slot 0..7
    int h = lane & 7;   // head 0..7
    f16x8 qf = *(const f16x8*)(q + (n << 6) + (h << 3));
    int rs = rowptr[n], re = rowptr[n + 1];
    const float scale = 0.35355339059327373f;
    float lsum = 0.f;
    float acc0 = 0.f, acc1 = 0.f, acc2 = 0.f, acc3 = 0.f;
    float acc4 = 0.f, acc5 = 0.f, acc6 = 0.f, acc7 = 0.f;
    for (int j0 = rs; j0 < re; j0 += 16) {
        int ja = j0 + e, jb = j0 + 8 + e;
        bool va = ja < re, vb = jb < re;
        int pa = scomb[va ? ja : rs];
        int pb = scomb[vb ? jb : rs];
        const f16* kpa = kv + ((size_t)(pa >> 11) << 7) + (h << 3);
        const f16* kpb = kv + ((size_t)(pb >> 11) << 7) + (h << 3);
        f16x8 ka = *(const f16x8*)(kpa);
        f16x8 vaf = *(const f16x8*)(kpa + 64);
        f16x8 ta = *(const f16x8*)(te + ((pa & 2047) << 6) + (h << 3));
        f16x8 kb2 = *(const f16x8*)(kpb);
        f16x8 vbf = *(const f16x8*)(kpb + 64);
        f16x8 tb = *(const f16x8*)(te + ((pb & 2047) << 6) + (h << 3));
        float ala = dot8(qf, ka + ta, 0.f) * scale;
        float alb = dot8(qf, kb2 + tb, 0.f) * scale;
        float wa = va ? __expf(ala) : 0.f;
        float wb = vb ? __expf(alb) : 0.f;
        lsum += wa + wb;
        f16x8 vta = vaf + ta;
        f16x8 vtb = vbf + tb;
        acc0 += wa * (float)vta[0] + wb * (float)vtb[0];
        acc1 += wa * (float)vta[1] + wb * (float)vtb[1];
        acc2 += wa * (float)vta[2] + wb * (float)vtb[2];
        acc3 += wa * (float)vta[3] + wb * (float)vtb[3];
        acc4 += wa * (float)vta[4] + wb * (float)vtb[4];
        acc5 += wa * (float)vta[5] + wb * (float)vtb[5];
        acc6 += wa * (float)vta[6] + wb * (float)vtb[6];
        acc7 += wa * (float)vta[7] + wb * (float)vtb[7];
    }
    // reduce across the 8 edge-slot lanes of each head
#pragma unroll
    for (int o = 8; o < 64; o <<= 1) {
        lsum += __shfl_xor(lsum, o);
        acc0 += __shfl_xor(acc0, o);
        acc1 += __shfl_xor(acc1, o);
        acc2 += __shfl_xor(acc2, o);
        acc3 += __shfl_xor(acc3, o);
        acc4 += __shfl_xor(acc4, o);
        acc5 += __shfl_xor(acc5, o);
        acc6 += __shfl_xor(acc6, o);
        acc7 += __shfl_xor(acc7, o);
    }
    float av = acc0;
    av = (e == 1) ? acc1 : av;
    av = (e == 2) ? acc2 : av;
    av = (e == 3) ? acc3 : av;
    av = (e == 4) ? acc4 : av;
    av = (e == 5) ? acc5 : av;
    av = (e == 6) ? acc6 : av;
    av = (e == 7) ? acc7 : av;
    int d = (h << 3) + e;
    float outv = av / (lsum + 1e-16f) + (float)sk[(n << 6) + d];
    if (do_ln) {
        float ssum = outv;
#pragma unroll
        for (int o = 1; o < 64; o <<= 1) ssum += __shfl_xor(ssum, o);
        float mu = ssum * (1.f / 64.f);
        float dv = outv - mu;
        float vs = dv * dv;
#pragma unroll
        for (int o = 1; o < 64; o <<= 1) vs += __shfl_xor(vs, o);
        float var = vs * (1.f / 64.f);
        float yv = ln_g[d] * dv / sqrtf(var + EPS) + ln_b[d];
        outv = fmaxf(yv, 0.f);
        xout[(n << 6) + d] = (f16)outv;
    } else {
        xout[(n << 6) + d] = (f16)outv;
        float p0 = outv * Wp[d * 2 + 0];
        float p1 = outv * Wp[d * 2 + 1];
#pragma unroll
        for (int o = 1; o < 64; o <<= 1) {
            p0 += __shfl_xor(p0, o);
            p1 += __shfl_xor(p1, o);
        }
        if (lane == 0) {
            pol[n * 2 + 0] = p0 + bp[0];
            pol[n * 2 + 1] = p1 + bp[1];
        }
    }
}

// ---------------- column sums for the graph mean
__global__ __launch_bounds__(256) void k_colsum(const f16* __restrict__ x16, float* __restrict__ gsum) {
    __shared__ float sh[256];
    int t = threadIdx.x;
    int col = t & 63;
    float acc = 0.f;
    for (int n = blockIdx.x * 4 + (t >> 6); n < N_NODES; n += gridDim.x * 4)
        acc += (float)x16[(n << 6) + col];
    sh[t] = acc;
    __syncthreads();
    if (t < 64) {
        float s = sh[t] + sh[t + 64] + sh[t + 128] + sh[t + 192];
        atomicAdd(&gsum[t], s);
    }
}

// ---------------- value head
__global__ __launch_bounds__(64) void k_value(
    const float* __restrict__ gsum, const float* __restrict__ Wv1,
    const float* __restrict__ bv1, const float* __restrict__ Wv2,
    const float* __restrict__ bv2, float* __restrict__ out) {
    int lane = threadIdx.x;
    float h = bv1[lane];
    for (int i = 0; i < HID; ++i) h += (gsum[i] * (1.f / N_NODES)) * Wv1[i * HID + lane];
    h = fmaxf(h, 0.f);
    float p = h * Wv2[lane];
#pragma unroll
    for (int o = 1; o < 64; o <<= 1) p += __shfl_xor(p, o);
    if (lane == 0) out[0] = tanhf(p + bv2[0]);
}

extern "C" void kernel_launch(void* const* d_in, const int* in_sizes, int n_in,
                              void* d_out, int out_size, void* d_ws, size_t ws_size,
                              hipStream_t stream) {
    const int* x_nodes = (const int*)d_in[0];
    const int* edge_index = (const int*)d_in[1];
    const int* edge_label = (const int*)d_in[2];
    const int* edge_sign = (const int*)d_in[3];
    const float* emb_strand = (const float*)d_in[4];
    const float* emb_pos = (const float*)d_in[5];
    const float* emb_sign = (const float*)d_in[6];
    const float* We = (const float*)d_in[7];
    const float* be = (const float*)d_in[8];
    const float* Wq = (const float*)d_in[9];
    const float* bq = (const float*)d_in[10];
    const float* Wk = (const float*)d_in[11];
    const float* bk = (const float*)d_in[12];
    const float* Wv = (const float*)d_in[13];
    const float* bv = (const float*)d_in[14];
    const float* Wedge = (const float*)d_in[15];
    const float* Wskip = (const float*)d_in[16];
    const float* bskip = (const float*)d_in[17];
    const float* ln_g = (const float*)d_in[18];
    const float* ln_b = (const float*)d_in[19];
    const float* Wp = (const float*)d_in[20];
    const float* bp = (const float*)d_in[21];
    const float* Wv1 = (const float*)d_in[22];
    const float* bv1 = (const float*)d_in[23];
    const float* Wv2 = (const float*)d_in[24];
    const float* bv2 = (const float*)d_in[25];
    float* out = (float*)d_out;

    const int* src = edge_index;
    const int* dst = edge_index + N_EDGES;

    char* ws = (char*)d_ws;
    size_t off = 0;
    auto alloc = [&](size_t bytes) -> void* {
        void* p = ws + off;
        off += (bytes + 255) & ~(size_t)255;
        return p;
    };
    f16* x16 = (f16*)alloc((size_t)N_NODES * HID * 2);
    f16* q = (f16*)alloc((size_t)N_NODES * HID * 2);
    f16* kv = (f16*)alloc((size_t)N_NODES * 128 * 2);
    f16* sk = (f16*)alloc((size_t)N_NODES * HID * 2);
    int* scomb = (int*)alloc((size_t)N_EDGES * 4);
    int2* binbuf = (int2*)alloc((size_t)NBUCK * BUCK_CAP * 8);
    int* rowptr = (int*)alloc((size_t)(N_NODES + 1) * 4);
    int* bcur = (int*)alloc((size_t)NBUCK * 4);
    int* bbase = (int*)alloc((size_t)NBUCK * 4);
    f16* TE = (f16*)alloc((size_t)LAYERS * NCOMB * HID * 2);
    f16* wcatT = (f16*)alloc((size_t)LAYERS * 256 * HID * 2);
    float* bcat = (float*)alloc((size_t)LAYERS * 256 * 4);
    float* gsum = (float*)alloc(64 * 4);

    hipMemsetAsync(bcur, 0, (size_t)NBUCK * 4, stream);

    k_node_feat<<<(N_NODES * HID + 255) / 256, 256, 0, stream>>>(x_nodes, emb_strand, emb_pos, x16);
    k_tabTE<<<NCOMB / 16, 256, 0, stream>>>(emb_strand, emb_sign, We, be, Wedge, TE);
    k_wprep<<<(LAYERS * 256 * HID + 255) / 256, 256, 0, stream>>>(
        Wq, bq, Wk, bk, Wv, bv, Wskip, bskip, wcatT, bcat);
    k_bin<<<BIN_NBLK, 256, 0, stream>>>(src, dst, edge_label, edge_sign, bcur, binbuf);
    k_bscan<<<1, 256, 0, stream>>>(bcur, bbase, rowptr, gsum);
    k_place<<<NBUCK, 256, 0, stream>>>(bcur, bbase, binbuf, rowptr, scomb);

    for (int l = 0; l < LAYERS; ++l) {
        k_proj<<<N_NODES / 16, 256, 0, stream>>>(
            x16, wcatT + (size_t)l * 256 * HID, bcat + (size_t)l * 256, q, kv, sk);
        int do_ln = (l < LAYERS - 1) ? 1 : 0;
        const float* lg = do_ln ? (ln_g + (size_t)l * HID) : ln_g;
        const float* lb = do_ln ? (ln_b + (size_t)l * HID) : ln_b;
        k_agg<<<(N_NODES + 3) / 4, 256, 0, stream>>>(
            q, kv, sk, TE + (size_t)l * NCOMB * HID, scomb, rowptr,
            lg, lb, x16, do_ln, Wp, bp, out);
    }

    k_colsum<<<128, 256, 0, stream>>>(x16, gsum);
    k_value<<<1, 64, 0, stream>>>(gsum, Wv1, bv1, Wv2, bv2, out + 2 * N_NODES);
}